// Round 1
// baseline (1475.257 us; speedup 1.0000x reference)
//
#include <hip/hip_runtime.h>
#include <hip/hip_bf16.h>

#define BATCH 2
#define SEQ   2048
#define DMODEL 2048
#define DINNER 4096
#define DXB   1024
#define NHEADS 64
#define NKV   16
#define HEADDIM 64
#define DSTATE 64
#define INTER 8192
#define DINPROJ 10304   // 4096 z + 1024 x + 1024 B + 4096 C + 64 dt
#define ROWS  (BATCH*SEQ)   // 4096
#define EPSV  1e-5f

typedef short short8 __attribute__((ext_vector_type(8)));
typedef float f32x4 __attribute__((ext_vector_type(4)));

static __device__ __forceinline__ unsigned short f2bf(float f) {
    unsigned int u = __float_as_uint(f);
    unsigned int r = (u + 0x7fffu + ((u >> 16) & 1u)) >> 16;
    return (unsigned short)r;
}
static __device__ __forceinline__ float bf2f(unsigned short h) {
    return __uint_as_float(((unsigned int)h) << 16);
}

// ---------------- f32 -> bf16 conversion (grid-stride, float4) ----------------
__global__ __launch_bounds__(256) void convk(const float* __restrict__ in,
                                             unsigned short* __restrict__ out, int n4) {
    int stride = gridDim.x * blockDim.x;
    for (int i = blockIdx.x * blockDim.x + threadIdx.x; i < n4; i += stride) {
        float4 v = ((const float4*)in)[i];
        ushort4 o;
        o.x = f2bf(v.x); o.y = f2bf(v.y); o.z = f2bf(v.z); o.w = f2bf(v.w);
        ((ushort4*)out)[i] = o;
    }
}

// ---------------- LayerNorm: one block per row, writes bf16 h ----------------
__global__ __launch_bounds__(256) void ln_kernel(const float* __restrict__ x,
                                                 const float* __restrict__ w,
                                                 const float* __restrict__ b,
                                                 unsigned short* __restrict__ hout) {
    int row = blockIdx.x;
    int t = threadIdx.x;
    const float* xr = x + (size_t)row * DMODEL;
    float v[8];
    float4 v0 = *(const float4*)&xr[t * 8];
    float4 v1 = *(const float4*)&xr[t * 8 + 4];
    v[0]=v0.x; v[1]=v0.y; v[2]=v0.z; v[3]=v0.w; v[4]=v1.x; v[5]=v1.y; v[6]=v1.z; v[7]=v1.w;
    float s = 0.f, s2 = 0.f;
    #pragma unroll
    for (int i = 0; i < 8; ++i) { s += v[i]; s2 += v[i]*v[i]; }
    #pragma unroll
    for (int off = 1; off < 64; off <<= 1) { s += __shfl_xor(s, off); s2 += __shfl_xor(s2, off); }
    __shared__ float sa[4], sb[4];
    int lane = t & 63, wv = t >> 6;
    if (lane == 0) { sa[wv] = s; sb[wv] = s2; }
    __syncthreads();
    s = sa[0]+sa[1]+sa[2]+sa[3];
    s2 = sb[0]+sb[1]+sb[2]+sb[3];
    float mu = s / DMODEL;
    float var = s2 / DMODEL - mu * mu;
    float sc = rsqrtf(var + EPSV);
    unsigned short* ho = hout + (size_t)row * DMODEL + t * 8;
    #pragma unroll
    for (int i = 0; i < 8; ++i) {
        int d = t * 8 + i;
        ho[i] = f2bf((v[i] - mu) * sc * w[d] + b[d]);
    }
}

// ---------------- bf16 MFMA GEMM: C[M,N] = A[M,K] * B[N,K]^T ----------------
// 128x128 tile, 4 waves (each 64x64 = 4x4 frags of 16x16x32), BK=32, reg-staged LDS.
// EPI 0: store f32. EPI 1: gelu(acc+bias) -> bf16. EPI 2: acc+bias+add1+add2 -> f32.
template <int EPI>
__global__ __launch_bounds__(256) void gemm_bt(
    const unsigned short* __restrict__ A, const unsigned short* __restrict__ B,
    int M, int N, int K,
    float* __restrict__ outF, unsigned short* __restrict__ outH,
    const float* __restrict__ bias, const float* __restrict__ add1,
    const float* __restrict__ add2) {
    __shared__ __align__(16) unsigned short As[128 * 32];
    __shared__ __align__(16) unsigned short Bs[128 * 32];
    int t = threadIdx.x, lane = t & 63, w = t >> 6;
    int wr = w >> 1, wc = w & 1;
    int brow = blockIdx.y * 128, bcol = blockIdx.x * 128;
    f32x4 acc[4][4] = {};
    int lr = lane & 15, kk = (lane >> 4) << 3;
    for (int k0 = 0; k0 < K; k0 += 32) {
        #pragma unroll
        for (int i = 0; i < 2; ++i) {
            int lin = i * 256 + t;
            int r = lin >> 2, k8 = (lin & 3) << 3;
            *(uint4*)&As[r * 32 + k8] = *(const uint4*)&A[(size_t)(brow + r) * K + k0 + k8];
            int bn = bcol + r; if (bn > N - 1) bn = N - 1;
            *(uint4*)&Bs[r * 32 + k8] = *(const uint4*)&B[(size_t)bn * K + k0 + k8];
        }
        __syncthreads();
        short8 af[4], bfr[4];
        #pragma unroll
        for (int f = 0; f < 4; ++f) {
            af[f]  = *(const short8*)&As[(wr * 64 + f * 16 + lr) * 32 + kk];
            bfr[f] = *(const short8*)&Bs[(wc * 64 + f * 16 + lr) * 32 + kk];
        }
        #pragma unroll
        for (int fm = 0; fm < 4; ++fm)
            #pragma unroll
            for (int fn = 0; fn < 4; ++fn)
                acc[fm][fn] = __builtin_amdgcn_mfma_f32_16x16x32_bf16(af[fm], bfr[fn], acc[fm][fn], 0, 0, 0);
        __syncthreads();
    }
    int rb = brow + wr * 64, cb = bcol + wc * 64;
    int rlane = (lane >> 4) << 2, clane = lane & 15;
    #pragma unroll
    for (int fm = 0; fm < 4; ++fm) {
        #pragma unroll
        for (int fn = 0; fn < 4; ++fn) {
            int col = cb + fn * 16 + clane;
            if (col < N) {
                #pragma unroll
                for (int j = 0; j < 4; ++j) {
                    int row = rb + fm * 16 + rlane + j;
                    size_t idx = (size_t)row * N + col;
                    float v = acc[fm][fn][j];
                    if constexpr (EPI == 0) {
                        outF[idx] = v;
                    } else if constexpr (EPI == 1) {
                        v += bias[col];
                        float g = 0.5f * v * (1.f + tanhf(0.7978845608f * (v + 0.044715f * v * v * v)));
                        outH[idx] = f2bf(g);
                    } else {
                        outF[idx] = v + bias[col] + add1[idx] + add2[idx];
                    }
                }
            }
        }
    }
}

// ---------------- dt: softplus + dA precompute ----------------
__global__ __launch_bounds__(256) void dtk(const float* __restrict__ zx,
                                           const float* __restrict__ dt_bias,
                                           const float* __restrict__ A_log,
                                           float* __restrict__ dtv, float* __restrict__ dAv) {
    int idx = blockIdx.x * 256 + threadIdx.x;   // < ROWS*NHEADS
    int h = idx & 63;
    size_t row = idx >> 6;
    float raw = zx[row * DINPROJ + 10240 + h] + dt_bias[h];
    float dt = raw > 20.f ? raw : log1pf(expf(raw));
    float A = -expf(A_log[h]);
    dtv[idx] = dt;
    dAv[idx] = expf(dt * A);
}

// ---------------- SSD scan: one block per (b,h), chunked staging ----------------
__global__ __launch_bounds__(256) void scan_kernel(const float* __restrict__ zx,
                                                   const float* __restrict__ dtv,
                                                   const float* __restrict__ dAv,
                                                   const float* __restrict__ Dp,
                                                   float* __restrict__ y) {
    int b = blockIdx.x >> 6;
    int h = blockIdx.x & 63;
    int g = h >> 2;                 // GQA kv-group
    int t = threadIdx.x;
    int p = t >> 2, nb = (t & 3) << 4;
    __shared__ float xs[64][64], Bsh[64][64], Csh[64][64];
    __shared__ float dts[64], dAs[64];
    float st[16];
    #pragma unroll
    for (int j = 0; j < 16; ++j) st[j] = 0.f;
    float Dph = Dp[h];
    for (int c = 0; c < SEQ / 64; ++c) {
        int l0 = c * 64;
        #pragma unroll
        for (int i = 0; i < 16; ++i) {
            int lin = i * 256 + t;
            int s = lin >> 6, d = lin & 63;
            size_t rowoff = (size_t)((b << 11) + l0 + s) * DINPROJ;
            xs[s][d]  = zx[rowoff + 4096 + g * 64 + d];
            Bsh[s][d] = zx[rowoff + 5120 + g * 64 + d];
            Csh[s][d] = zx[rowoff + 6144 + h * 64 + d];
        }
        if (t < 64) {
            int idx = ((b << 11) + l0 + t) * 64 + h;
            dts[t] = dtv[idx];
            dAs[t] = dAv[idx];
        }
        __syncthreads();
        for (int s = 0; s < 64; ++s) {
            float dA = dAs[s], dt = dts[s];
            float xp = xs[s][p];
            float coef = dt * xp;
            float ysum = 0.f;
            #pragma unroll
            for (int j = 0; j < 16; ++j) {
                st[j] = st[j] * dA + coef * Bsh[s][nb + j];
                ysum += st[j] * Csh[s][nb + j];
            }
            ysum += __shfl_xor(ysum, 1);
            ysum += __shfl_xor(ysum, 2);
            if ((t & 3) == 0)
                y[(size_t)((b << 11) + l0 + s) * DINNER + h * 64 + p] = ysum + Dph * xp;
        }
        __syncthreads();
    }
}

// ---------------- gate (silu) + RMSNorm -> bf16 yf ----------------
__global__ __launch_bounds__(256) void gate_kernel(const float* __restrict__ y,
                                                   const float* __restrict__ zx,
                                                   const float* __restrict__ norm_w,
                                                   unsigned short* __restrict__ yf) {
    int row = blockIdx.x;
    int t = threadIdx.x;
    float v[16];
    float s2 = 0.f;
    #pragma unroll
    for (int i = 0; i < 16; ++i) {
        int d = i * 256 + t;
        float yv = y[(size_t)row * DINNER + d];
        float zv = zx[(size_t)row * DINPROJ + d];
        float gt = zv / (1.f + expf(-zv));
        v[i] = yv * gt;
        s2 += v[i] * v[i];
    }
    #pragma unroll
    for (int off = 1; off < 64; off <<= 1) s2 += __shfl_xor(s2, off);
    __shared__ float sb[4];
    int lane = t & 63, wv = t >> 6;
    if (lane == 0) sb[wv] = s2;
    __syncthreads();
    s2 = sb[0] + sb[1] + sb[2] + sb[3];
    float sc = rsqrtf(s2 / DINNER + EPSV);
    #pragma unroll
    for (int i = 0; i < 16; ++i) {
        int d = i * 256 + t;
        yf[(size_t)row * DINNER + d] = f2bf(v[i] * sc * norm_w[d]);
    }
}

extern "C" void kernel_launch(void* const* d_in, const int* in_sizes, int n_in,
                              void* d_out, int out_size, void* d_ws, size_t ws_size,
                              hipStream_t stream) {
    const float* hid   = (const float*)d_in[0];
    const float* ln_w  = (const float*)d_in[1];
    const float* ln_b  = (const float*)d_in[2];
    const float* w_inp = (const float*)d_in[3];
    const float* dtb   = (const float*)d_in[4];
    const float* A_log = (const float*)d_in[5];
    const float* Dp    = (const float*)d_in[6];
    const float* nw    = (const float*)d_in[7];
    const float* w_out = (const float*)d_in[8];
    const float* w_fc1 = (const float*)d_in[9];
    const float* fc1_b = (const float*)d_in[10];
    const float* w_fc2 = (const float*)d_in[11];
    const float* fc2_b = (const float*)d_in[12];

    char* ws = (char*)d_ws;
    size_t off = 0;
    auto alloc = [&](size_t bytes) { size_t o = off; off += (bytes + 255) & ~(size_t)255; return o; };
    size_t o_h    = alloc((size_t)ROWS * DMODEL * 2);        // h bf16
    size_t o_w    = alloc((size_t)DINPROJ * DMODEL * 2);     // shared weight bf16 buffer (max size)
    size_t o_zx   = alloc((size_t)ROWS * DINPROJ * 4);       // zxbcdt f32 (later aliased by gelu bf16)
    size_t o_dtv  = alloc((size_t)ROWS * NHEADS * 4);
    size_t o_dAv  = alloc((size_t)ROWS * NHEADS * 4);
    size_t o_y    = alloc((size_t)ROWS * DINNER * 4);        // y f32 (later aliased by mamba_out f32)
    size_t o_yf   = alloc((size_t)ROWS * DINNER * 2);        // yf bf16

    unsigned short* h_bf  = (unsigned short*)(ws + o_h);
    unsigned short* wbuf  = (unsigned short*)(ws + o_w);
    float* zx             = (float*)(ws + o_zx);
    float* dtv            = (float*)(ws + o_dtv);
    float* dAv            = (float*)(ws + o_dAv);
    float* ybuf           = (float*)(ws + o_y);
    unsigned short* yf    = (unsigned short*)(ws + o_yf);
    unsigned short* gelu  = (unsigned short*)(ws + o_zx);    // alias: zx dead after gate
    float* mamba          = (float*)(ws + o_y);              // alias: y dead after gate
    float* outF           = (float*)d_out;

    // 1) LayerNorm -> h (bf16)
    ln_kernel<<<ROWS, 256, 0, stream>>>(hid, ln_w, ln_b, h_bf);
    // 2) in_proj GEMM: zxbcdt = h @ W_in^T  (f32 out)
    convk<<<2048, 256, 0, stream>>>(w_inp, wbuf, (DINPROJ * DMODEL) / 4);
    gemm_bt<0><<<dim3((DINPROJ + 127) / 128, ROWS / 128), 256, 0, stream>>>(
        h_bf, wbuf, ROWS, DINPROJ, DMODEL, zx, nullptr, nullptr, nullptr, nullptr);
    // 3) dt softplus + dA
    dtk<<<(ROWS * NHEADS) / 256, 256, 0, stream>>>(zx, dtb, A_log, dtv, dAv);
    // 4) SSD scan -> y (includes +Dp*x)
    scan_kernel<<<BATCH * NHEADS, 256, 0, stream>>>(zx, dtv, dAv, Dp, ybuf);
    // 5) gate + RMSNorm -> yf (bf16)
    gate_kernel<<<ROWS, 256, 0, stream>>>(ybuf, zx, nw, yf);
    // 6) out_proj GEMM -> mamba_out (f32)
    convk<<<2048, 256, 0, stream>>>(w_out, wbuf, (DMODEL * DINNER) / 4);
    gemm_bt<0><<<dim3(DMODEL / 128, ROWS / 128), 256, 0, stream>>>(
        yf, wbuf, ROWS, DMODEL, DINNER, mamba, nullptr, nullptr, nullptr, nullptr);
    // 7) fc1 GEMM + gelu -> gelu (bf16, aliases zx)
    convk<<<2048, 256, 0, stream>>>(w_fc1, wbuf, (INTER * DMODEL) / 4);
    gemm_bt<1><<<dim3(INTER / 128, ROWS / 128), 256, 0, stream>>>(
        h_bf, wbuf, ROWS, INTER, DMODEL, nullptr, gelu, fc1_b, nullptr, nullptr);
    // 8) fc2 GEMM + bias + mamba_out + residual -> d_out (f32)
    convk<<<2048, 256, 0, stream>>>(w_fc2, wbuf, (DMODEL * INTER) / 4);
    gemm_bt<2><<<dim3(DMODEL / 128, ROWS / 128), 256, 0, stream>>>(
        gelu, wbuf, ROWS, DMODEL, INTER, outF, nullptr, fc2_b, mamba, hid);
}

// Round 2
// 1053.624 us; speedup vs baseline: 1.4002x; 1.4002x over previous
//
#include <hip/hip_runtime.h>
#include <hip/hip_bf16.h>

#define BATCH 2
#define SEQ   2048
#define DMODEL 2048
#define DINNER 4096
#define DXB   1024
#define NHEADS 64
#define NKV   16
#define HEADDIM 64
#define DSTATE 64
#define INTER 8192
#define DINPROJ 10304   // 4096 z + 1024 x + 1024 B + 4096 C + 64 dt
#define ROWS  (BATCH*SEQ)   // 4096
#define NC    32            // chunks per sequence
#define EPSV  1e-5f

typedef short short8 __attribute__((ext_vector_type(8)));
typedef float f32x4 __attribute__((ext_vector_type(4)));

static __device__ __forceinline__ unsigned short f2bf(float f) {
    unsigned int u = __float_as_uint(f);
    unsigned int r = (u + 0x7fffu + ((u >> 16) & 1u)) >> 16;
    return (unsigned short)r;
}
static __device__ __forceinline__ float bf2f(unsigned short h) {
    return __uint_as_float(((unsigned int)h) << 16);
}

// ---------------- f32 -> bf16 conversion (grid-stride, float4) ----------------
__global__ __launch_bounds__(256) void convk(const float* __restrict__ in,
                                             unsigned short* __restrict__ out, int n4) {
    int stride = gridDim.x * blockDim.x;
    for (int i = blockIdx.x * blockDim.x + threadIdx.x; i < n4; i += stride) {
        float4 v = ((const float4*)in)[i];
        ushort4 o;
        o.x = f2bf(v.x); o.y = f2bf(v.y); o.z = f2bf(v.z); o.w = f2bf(v.w);
        ((ushort4*)out)[i] = o;
    }
}

// ---------------- LayerNorm: one block per row, writes bf16 h ----------------
__global__ __launch_bounds__(256) void ln_kernel(const float* __restrict__ x,
                                                 const float* __restrict__ w,
                                                 const float* __restrict__ b,
                                                 unsigned short* __restrict__ hout) {
    int row = blockIdx.x;
    int t = threadIdx.x;
    const float* xr = x + (size_t)row * DMODEL;
    float v[8];
    float4 v0 = *(const float4*)&xr[t * 8];
    float4 v1 = *(const float4*)&xr[t * 8 + 4];
    v[0]=v0.x; v[1]=v0.y; v[2]=v0.z; v[3]=v0.w; v[4]=v1.x; v[5]=v1.y; v[6]=v1.z; v[7]=v1.w;
    float s = 0.f, s2 = 0.f;
    #pragma unroll
    for (int i = 0; i < 8; ++i) { s += v[i]; s2 += v[i]*v[i]; }
    #pragma unroll
    for (int off = 1; off < 64; off <<= 1) { s += __shfl_xor(s, off); s2 += __shfl_xor(s2, off); }
    __shared__ float sa[4], sb[4];
    int lane = t & 63, wv = t >> 6;
    if (lane == 0) { sa[wv] = s; sb[wv] = s2; }
    __syncthreads();
    s = sa[0]+sa[1]+sa[2]+sa[3];
    s2 = sb[0]+sb[1]+sb[2]+sb[3];
    float mu = s / DMODEL;
    float var = s2 / DMODEL - mu * mu;
    float sc = rsqrtf(var + EPSV);
    unsigned short* ho = hout + (size_t)row * DMODEL + t * 8;
    #pragma unroll
    for (int i = 0; i < 8; ++i) {
        int d = t * 8 + i;
        ho[i] = f2bf((v[i] - mu) * sc * w[d] + b[d]);
    }
}

// ---------------- bf16 MFMA GEMM: C[M,N] = A[M,K] * B[N,K]^T ----------------
// EPI 0: f32. EPI 1: gelu(acc+bias)->bf16. EPI 2: acc+bias+add1+add2->f32. EPI 3: bf16.
template <int EPI>
__global__ __launch_bounds__(256) void gemm_bt(
    const unsigned short* __restrict__ A, const unsigned short* __restrict__ B,
    int M, int N, int K,
    float* __restrict__ outF, unsigned short* __restrict__ outH,
    const float* __restrict__ bias, const float* __restrict__ add1,
    const float* __restrict__ add2) {
    __shared__ __align__(16) unsigned short As[128 * 32];
    __shared__ __align__(16) unsigned short Bs[128 * 32];
    int t = threadIdx.x, lane = t & 63, w = t >> 6;
    int wr = w >> 1, wc = w & 1;
    int brow = blockIdx.y * 128, bcol = blockIdx.x * 128;
    f32x4 acc[4][4] = {};
    int lr = lane & 15, kk = (lane >> 4) << 3;
    for (int k0 = 0; k0 < K; k0 += 32) {
        #pragma unroll
        for (int i = 0; i < 2; ++i) {
            int lin = i * 256 + t;
            int r = lin >> 2, k8 = (lin & 3) << 3;
            *(uint4*)&As[r * 32 + k8] = *(const uint4*)&A[(size_t)(brow + r) * K + k0 + k8];
            int bn = bcol + r; if (bn > N - 1) bn = N - 1;
            *(uint4*)&Bs[r * 32 + k8] = *(const uint4*)&B[(size_t)bn * K + k0 + k8];
        }
        __syncthreads();
        short8 af[4], bfr[4];
        #pragma unroll
        for (int f = 0; f < 4; ++f) {
            af[f]  = *(const short8*)&As[(wr * 64 + f * 16 + lr) * 32 + kk];
            bfr[f] = *(const short8*)&Bs[(wc * 64 + f * 16 + lr) * 32 + kk];
        }
        #pragma unroll
        for (int fm = 0; fm < 4; ++fm)
            #pragma unroll
            for (int fn = 0; fn < 4; ++fn)
                acc[fm][fn] = __builtin_amdgcn_mfma_f32_16x16x32_bf16(af[fm], bfr[fn], acc[fm][fn], 0, 0, 0);
        __syncthreads();
    }
    int rb = brow + wr * 64, cb = bcol + wc * 64;
    int rlane = (lane >> 4) << 2, clane = lane & 15;
    #pragma unroll
    for (int fm = 0; fm < 4; ++fm) {
        #pragma unroll
        for (int fn = 0; fn < 4; ++fn) {
            int col = cb + fn * 16 + clane;
            if (col < N) {
                #pragma unroll
                for (int j = 0; j < 4; ++j) {
                    int row = rb + fm * 16 + rlane + j;
                    size_t idx = (size_t)row * N + col;
                    float v = acc[fm][fn][j];
                    if constexpr (EPI == 0) {
                        outF[idx] = v;
                    } else if constexpr (EPI == 1) {
                        v += bias[col];
                        float g = 0.5f * v * (1.f + tanhf(0.7978845608f * (v + 0.044715f * v * v * v)));
                        outH[idx] = f2bf(g);
                    } else if constexpr (EPI == 2) {
                        outF[idx] = v + bias[col] + add1[idx] + add2[idx];
                    } else {
                        outH[idx] = f2bf(v);
                    }
                }
            }
        }
    }
}

// ---------------- dt: softplus + dt*A precompute ----------------
__global__ __launch_bounds__(256) void dtk(const unsigned short* __restrict__ zx,
                                           const float* __restrict__ dt_bias,
                                           const float* __restrict__ A_log,
                                           float* __restrict__ dtv, float* __restrict__ dtA) {
    int idx = blockIdx.x * 256 + threadIdx.x;   // < ROWS*NHEADS
    int h = idx & 63;
    size_t row = idx >> 6;
    float raw = bf2f(zx[row * DINPROJ + 10240 + h]) + dt_bias[h];
    float dt = raw > 20.f ? raw : log1pf(expf(raw));
    dtv[idx] = dt;
    dtA[idx] = dt * (-expf(A_log[h]));
}

// 64x64x64 bf16 MFMA: out rows = rows of Al, out cols = rows of Bl, K = inner 64.
// wave w computes output rows w*16..w*16+15 (4 col-frags in acc[0..3]).
static __device__ __forceinline__ void mm64(const unsigned short* Al, const unsigned short* Bl,
                                            f32x4* acc, int w, int lane) {
    int lr = lane & 15, kg = (lane >> 4) << 3;
    #pragma unroll
    for (int ks = 0; ks < 2; ++ks) {
        short8 a = *(const short8*)&Al[(w * 16 + lr) * 64 + ks * 32 + kg];
        #pragma unroll
        for (int fn = 0; fn < 4; ++fn) {
            short8 bb = *(const short8*)&Bl[(fn * 16 + lr) * 64 + ks * 32 + kg];
            acc[fn] = __builtin_amdgcn_mfma_f32_16x16x32_bf16(a, bb, acc[fn], 0, 0, 0);
        }
    }
}

// ---------------- K1: per-(b,h,chunk) intra-chunk work ----------------
// Writes: pcum (exp inclusive decay cumprod), y_intra (bf16), S_c (bf16).
__global__ __launch_bounds__(256) void chunk_front(const unsigned short* __restrict__ zx,
                                                   const float* __restrict__ dtv,
                                                   const float* __restrict__ dtA,
                                                   float* __restrict__ pcum,
                                                   unsigned short* __restrict__ ybuf,
                                                   unsigned short* __restrict__ Sbuf) {
    __shared__ __align__(16) unsigned short Cs[64*64], Bsr[64*64], Btr[64*64],
                                            Xtr[64*64], Xw[64*64], Wsm[64*64];
    __shared__ float dts[64], clg[64];
    int t = threadIdx.x, lane = t & 63, w = t >> 6;
    int bid = blockIdx.x;
    int c = bid & 31, h = (bid >> 5) & 63, b = bid >> 11, g = h >> 2;
    int row0 = (b << 11) + (c << 6);

    if (t < 64) {
        dts[t] = dtv[(size_t)(row0 + t) * 64 + h];
        float v = dtA[(size_t)(row0 + t) * 64 + h];
        #pragma unroll
        for (int off = 1; off < 64; off <<= 1) {
            float o = __shfl_up(v, off);
            if (lane >= off) v += o;
        }
        clg[t] = v;
        pcum[(size_t)(row0 + t) * 64 + h] = expf(v);
    }
    ushort4 xr[4];
    #pragma unroll
    for (int i = 0; i < 4; ++i) {
        int q = i * 256 + t, s = q >> 4, d4 = (q & 15) << 2;
        const unsigned short* rp = zx + (size_t)(row0 + s) * DINPROJ;
        ushort4 cv = *(const ushort4*)&rp[6144 + h * 64 + d4];
        *(ushort4*)&Cs[s * 64 + d4] = cv;
        ushort4 bv = *(const ushort4*)&rp[5120 + g * 64 + d4];
        *(ushort4*)&Bsr[s * 64 + d4] = bv;
        Btr[(d4 + 0) * 64 + s] = bv.x; Btr[(d4 + 1) * 64 + s] = bv.y;
        Btr[(d4 + 2) * 64 + s] = bv.z; Btr[(d4 + 3) * 64 + s] = bv.w;
        ushort4 xv = *(const ushort4*)&rp[4096 + g * 64 + d4];
        Xtr[(d4 + 0) * 64 + s] = xv.x; Xtr[(d4 + 1) * 64 + s] = xv.y;
        Xtr[(d4 + 2) * 64 + s] = xv.z; Xtr[(d4 + 3) * 64 + s] = xv.w;
        xr[i] = xv;
    }
    __syncthreads();
    float cl63 = clg[63];
    #pragma unroll
    for (int i = 0; i < 4; ++i) {
        int q = i * 256 + t, s = q >> 4, d4 = (q & 15) << 2;
        float ws = dts[s] * expf(cl63 - clg[s]);
        Xw[(d4 + 0) * 64 + s] = f2bf(bf2f(xr[i].x) * ws);
        Xw[(d4 + 1) * 64 + s] = f2bf(bf2f(xr[i].y) * ws);
        Xw[(d4 + 2) * 64 + s] = f2bf(bf2f(xr[i].z) * ws);
        Xw[(d4 + 3) * 64 + s] = f2bf(bf2f(xr[i].w) * ws);
    }
    __syncthreads();
    // G = C @ B^T, then mask -> W (bf16, row-major [t][r])
    f32x4 accG[4] = {};
    mm64(Cs, Bsr, accG, w, lane);
    int rl = (lane >> 4) << 2, cl = lane & 15;
    #pragma unroll
    for (int fn = 0; fn < 4; ++fn) {
        #pragma unroll
        for (int j = 0; j < 4; ++j) {
            int tr = w * 16 + rl + j, rc = fn * 16 + cl;
            float val = 0.f;
            if (rc <= tr) val = accG[fn][j] * expf(clg[tr] - clg[rc]) * dts[rc];
            Wsm[tr * 64 + rc] = f2bf(val);
        }
    }
    __syncthreads();
    // y_intra[t][p] = sum_r W[t][r] x_r[p];  S[p][n] = sum_r w_r x_r[p] B_r[n]
    f32x4 accY[4] = {};
    mm64(Wsm, Xtr, accY, w, lane);
    f32x4 accS[4] = {};
    mm64(Xw, Btr, accS, w, lane);
    size_t cb = (size_t)((((b << 6) + h) << 5) + c) * 4096;
    #pragma unroll
    for (int fn = 0; fn < 4; ++fn) {
        #pragma unroll
        for (int j = 0; j < 4; ++j) {
            int tr = w * 16 + rl + j, pc = fn * 16 + cl;
            ybuf[(size_t)(row0 + tr) * DINNER + h * 64 + pc] = f2bf(accY[fn][j]);
            Sbuf[cb + tr * 64 + pc] = f2bf(accS[fn][j]);
        }
    }
}

// ---------------- K2: inter-chunk state recurrence (in-place S -> H0) ----------------
__global__ __launch_bounds__(256) void chunk_state(unsigned short* __restrict__ SH,
                                                   const float* __restrict__ pcum) {
    int b = blockIdx.x >> 6, h = blockIdx.x & 63, t = threadIdx.x;
    float H[16];
    #pragma unroll
    for (int j = 0; j < 16; ++j) H[j] = 0.f;
    for (int c = 0; c < NC; ++c) {
        size_t base = (size_t)((((b << 6) + h) << 5) + c) * 4096;
        float Tc = pcum[(size_t)((b << 11) + (c << 6) + 63) * 64 + h];
        #pragma unroll
        for (int j = 0; j < 16; ++j) {
            int e = j * 256 + t;
            unsigned short sv = SH[base + e];
            SH[base + e] = f2bf(H[j]);         // H0(c): state BEFORE chunk c
            H[j] = H[j] * Tc + bf2f(sv);       // advance past chunk c
        }
    }
}

// ---------------- K3: y += p_t * (C_t . H0) + Dp * x ----------------
__global__ __launch_bounds__(256) void chunk_back(const unsigned short* __restrict__ zx,
                                                  const unsigned short* __restrict__ SH,
                                                  const float* __restrict__ pcum,
                                                  const float* __restrict__ Dp,
                                                  unsigned short* __restrict__ ybuf) {
    __shared__ __align__(16) unsigned short Cs[64*64], Hs[64*64];
    __shared__ float ps[64];
    int t = threadIdx.x, lane = t & 63, w = t >> 6;
    int bid = blockIdx.x;
    int c = bid & 31, h = (bid >> 5) & 63, b = bid >> 11, g = h >> 2;
    int row0 = (b << 11) + (c << 6);
    size_t cb = (size_t)((((b << 6) + h) << 5) + c) * 4096;
    #pragma unroll
    for (int i = 0; i < 4; ++i) {
        int q = i * 256 + t, s = q >> 4, d4 = (q & 15) << 2;
        *(ushort4*)&Cs[s * 64 + d4] =
            *(const ushort4*)&zx[(size_t)(row0 + s) * DINPROJ + 6144 + h * 64 + d4];
        *(ushort4*)&Hs[s * 64 + d4] = *(const ushort4*)&SH[cb + s * 64 + d4];
    }
    if (t < 64) ps[t] = pcum[(size_t)(row0 + t) * 64 + h];
    __syncthreads();
    f32x4 acc[4] = {};
    mm64(Cs, Hs, acc, w, lane);
    float Dph = Dp[h];
    int rl = (lane >> 4) << 2, cl = lane & 15;
    #pragma unroll
    for (int fn = 0; fn < 4; ++fn) {
        #pragma unroll
        for (int j = 0; j < 4; ++j) {
            int tr = w * 16 + rl + j, pc = fn * 16 + cl;
            size_t yi = (size_t)(row0 + tr) * DINNER + h * 64 + pc;
            float xv = bf2f(zx[(size_t)(row0 + tr) * DINPROJ + 4096 + g * 64 + pc]);
            ybuf[yi] = f2bf(bf2f(ybuf[yi]) + acc[fn][j] * ps[tr] + Dph * xv);
        }
    }
}

// ---------------- gate (silu) + RMSNorm -> bf16 yf ----------------
__global__ __launch_bounds__(256) void gate_kernel(const unsigned short* __restrict__ y,
                                                   const unsigned short* __restrict__ zx,
                                                   const float* __restrict__ norm_w,
                                                   unsigned short* __restrict__ yf) {
    int row = blockIdx.x;
    int t = threadIdx.x;
    float v[16];
    float s2 = 0.f;
    #pragma unroll
    for (int i = 0; i < 16; ++i) {
        int d = i * 256 + t;
        float yv = bf2f(y[(size_t)row * DINNER + d]);
        float zv = bf2f(zx[(size_t)row * DINPROJ + d]);
        float gt = zv / (1.f + expf(-zv));
        v[i] = yv * gt;
        s2 += v[i] * v[i];
    }
    #pragma unroll
    for (int off = 1; off < 64; off <<= 1) s2 += __shfl_xor(s2, off);
    __shared__ float sb[4];
    int lane = t & 63, wv = t >> 6;
    if (lane == 0) sb[wv] = s2;
    __syncthreads();
    s2 = sb[0] + sb[1] + sb[2] + sb[3];
    float sc = rsqrtf(s2 / DINNER + EPSV);
    #pragma unroll
    for (int i = 0; i < 16; ++i) {
        int d = i * 256 + t;
        yf[(size_t)row * DINNER + d] = f2bf(v[i] * sc * norm_w[d]);
    }
}

extern "C" void kernel_launch(void* const* d_in, const int* in_sizes, int n_in,
                              void* d_out, int out_size, void* d_ws, size_t ws_size,
                              hipStream_t stream) {
    const float* hid   = (const float*)d_in[0];
    const float* ln_w  = (const float*)d_in[1];
    const float* ln_b  = (const float*)d_in[2];
    const float* w_inp = (const float*)d_in[3];
    const float* dtb   = (const float*)d_in[4];
    const float* A_log = (const float*)d_in[5];
    const float* Dp    = (const float*)d_in[6];
    const float* nw    = (const float*)d_in[7];
    const float* w_out = (const float*)d_in[8];
    const float* w_fc1 = (const float*)d_in[9];
    const float* fc1_b = (const float*)d_in[10];
    const float* w_fc2 = (const float*)d_in[11];
    const float* fc2_b = (const float*)d_in[12];

    char* ws = (char*)d_ws;
    size_t off = 0;
    auto alloc = [&](size_t bytes) { size_t o = off; off += (bytes + 255) & ~(size_t)255; return o; };
    size_t o_h    = alloc((size_t)ROWS * DMODEL * 2);        // h bf16
    size_t o_w    = alloc((size_t)DINPROJ * DMODEL * 2);     // shared weight bf16 buffer
    size_t o_zx   = alloc((size_t)ROWS * DINPROJ * 2);       // zxbcdt bf16 (later: gelu bf16)
    size_t o_dt   = alloc((size_t)ROWS * NHEADS * 4);        // dt f32
    size_t o_dta  = alloc((size_t)ROWS * NHEADS * 4);        // dt*A f32
    size_t o_pc   = alloc((size_t)ROWS * NHEADS * 4);        // pcum f32
    size_t o_y    = alloc((size_t)ROWS * DINNER * 2);        // y bf16 (later: mamba f32, same size)
    size_t o_yf   = alloc((size_t)ROWS * DINNER * 2);        // yf bf16
    size_t o_S    = alloc((size_t)BATCH * NHEADS * NC * HEADDIM * DSTATE * 2); // S->H0 bf16

    unsigned short* h_bf  = (unsigned short*)(ws + o_h);
    unsigned short* wbuf  = (unsigned short*)(ws + o_w);
    unsigned short* zx    = (unsigned short*)(ws + o_zx);
    float* dtv            = (float*)(ws + o_dt);
    float* dtA            = (float*)(ws + o_dta);
    float* pcum           = (float*)(ws + o_pc);
    unsigned short* ybuf  = (unsigned short*)(ws + o_y);
    unsigned short* yf    = (unsigned short*)(ws + o_yf);
    unsigned short* Sbuf  = (unsigned short*)(ws + o_S);
    unsigned short* gelu  = (unsigned short*)(ws + o_zx);    // alias: zx dead after gate
    float* mamba          = (float*)(ws + o_y);              // alias: y dead after gate
    float* outF           = (float*)d_out;

    // 1) LayerNorm -> h (bf16)
    ln_kernel<<<ROWS, 256, 0, stream>>>(hid, ln_w, ln_b, h_bf);
    // 2) in_proj GEMM -> zx (bf16)
    convk<<<2048, 256, 0, stream>>>(w_inp, wbuf, (DINPROJ * DMODEL) / 4);
    gemm_bt<3><<<dim3((DINPROJ + 127) / 128, ROWS / 128), 256, 0, stream>>>(
        h_bf, wbuf, ROWS, DINPROJ, DMODEL, nullptr, zx, nullptr, nullptr, nullptr);
    // 3) dt softplus + dt*A
    dtk<<<(ROWS * NHEADS) / 256, 256, 0, stream>>>(zx, dtb, A_log, dtv, dtA);
    // 4) chunked SSD scan
    chunk_front<<<BATCH * NHEADS * NC, 256, 0, stream>>>(zx, dtv, dtA, pcum, ybuf, Sbuf);
    chunk_state<<<BATCH * NHEADS, 256, 0, stream>>>(Sbuf, pcum);
    chunk_back<<<BATCH * NHEADS * NC, 256, 0, stream>>>(zx, Sbuf, pcum, Dp, ybuf);
    // 5) gate + RMSNorm -> yf (bf16)
    gate_kernel<<<ROWS, 256, 0, stream>>>(ybuf, zx, nw, yf);
    // 6) out_proj GEMM -> mamba (f32)
    convk<<<2048, 256, 0, stream>>>(w_out, wbuf, (DMODEL * DINNER) / 4);
    gemm_bt<0><<<dim3(DMODEL / 128, ROWS / 128), 256, 0, stream>>>(
        yf, wbuf, ROWS, DMODEL, DINNER, mamba, nullptr, nullptr, nullptr, nullptr);
    // 7) fc1 GEMM + gelu -> gelu (bf16, aliases zx)
    convk<<<2048, 256, 0, stream>>>(w_fc1, wbuf, (INTER * DMODEL) / 4);
    gemm_bt<1><<<dim3(INTER / 128, ROWS / 128), 256, 0, stream>>>(
        h_bf, wbuf, ROWS, INTER, DMODEL, nullptr, gelu, fc1_b, nullptr, nullptr);
    // 8) fc2 GEMM + bias + mamba + residual -> d_out (f32)
    convk<<<2048, 256, 0, stream>>>(w_fc2, wbuf, (DMODEL * INTER) / 4);
    gemm_bt<2><<<dim3(DMODEL / 128, ROWS / 128), 256, 0, stream>>>(
        gelu, wbuf, ROWS, DMODEL, INTER, outF, nullptr, fc2_b, mamba, hid);
}

// Round 3
// 1031.474 us; speedup vs baseline: 1.4302x; 1.0215x over previous
//
#include <hip/hip_runtime.h>
#include <hip/hip_bf16.h>

#define BATCH 2
#define SEQ   2048
#define DMODEL 2048
#define DINNER 4096
#define DXB   1024
#define NHEADS 64
#define NKV   16
#define HEADDIM 64
#define DSTATE 64
#define INTER 8192
#define DINPROJ 10304   // 4096 z + 1024 x + 1024 B + 4096 C + 64 dt
#define ROWS  (BATCH*SEQ)   // 4096
#define NC    32            // chunks per sequence
#define EPSV  1e-5f

typedef short short8 __attribute__((ext_vector_type(8)));
typedef float f32x4 __attribute__((ext_vector_type(4)));

typedef const __attribute__((address_space(1))) unsigned int cg_u32;
typedef __attribute__((address_space(3))) unsigned int ls_u32;

static __device__ __forceinline__ void gll16(const void* g, void* l) {
    __builtin_amdgcn_global_load_lds((cg_u32*)g, (ls_u32*)l, 16, 0, 0);
}

static __device__ __forceinline__ unsigned short f2bf(float f) {
    unsigned int u = __float_as_uint(f);
    unsigned int r = (u + 0x7fffu + ((u >> 16) & 1u)) >> 16;
    return (unsigned short)r;
}
static __device__ __forceinline__ float bf2f(unsigned short h) {
    return __uint_as_float(((unsigned int)h) << 16);
}

// ---------------- f32 -> bf16 conversion (grid-stride, float4) ----------------
__global__ __launch_bounds__(256) void convk(const float* __restrict__ in,
                                             unsigned short* __restrict__ out, int n4) {
    int stride = gridDim.x * blockDim.x;
    for (int i = blockIdx.x * blockDim.x + threadIdx.x; i < n4; i += stride) {
        float4 v = ((const float4*)in)[i];
        ushort4 o;
        o.x = f2bf(v.x); o.y = f2bf(v.y); o.z = f2bf(v.z); o.w = f2bf(v.w);
        ((ushort4*)out)[i] = o;
    }
}

// ---------------- LayerNorm: one block per row, writes bf16 h ----------------
__global__ __launch_bounds__(256) void ln_kernel(const float* __restrict__ x,
                                                 const float* __restrict__ w,
                                                 const float* __restrict__ b,
                                                 unsigned short* __restrict__ hout) {
    int row = blockIdx.x;
    int t = threadIdx.x;
    const float* xr = x + (size_t)row * DMODEL;
    float v[8];
    float4 v0 = *(const float4*)&xr[t * 8];
    float4 v1 = *(const float4*)&xr[t * 8 + 4];
    v[0]=v0.x; v[1]=v0.y; v[2]=v0.z; v[3]=v0.w; v[4]=v1.x; v[5]=v1.y; v[6]=v1.z; v[7]=v1.w;
    float s = 0.f, s2 = 0.f;
    #pragma unroll
    for (int i = 0; i < 8; ++i) { s += v[i]; s2 += v[i]*v[i]; }
    #pragma unroll
    for (int off = 1; off < 64; off <<= 1) { s += __shfl_xor(s, off); s2 += __shfl_xor(s2, off); }
    __shared__ float sa[4], sb[4];
    int lane = t & 63, wv = t >> 6;
    if (lane == 0) { sa[wv] = s; sb[wv] = s2; }
    __syncthreads();
    s = sa[0]+sa[1]+sa[2]+sa[3];
    s2 = sb[0]+sb[1]+sb[2]+sb[3];
    float mu = s / DMODEL;
    float var = s2 / DMODEL - mu * mu;
    float sc = rsqrtf(var + EPSV);
    unsigned short* ho = hout + (size_t)row * DMODEL + t * 8;
    #pragma unroll
    for (int i = 0; i < 8; ++i) {
        int d = t * 8 + i;
        ho[i] = f2bf((v[i] - mu) * sc * w[d] + b[d]);
    }
}

// ---------------- bf16 MFMA GEMM: C[M,N] = A[M,K] * B[N,K]^T ----------------
// m97 structure: 128x128 tile, BK=32, global_load_lds width-16 staging,
// 1-D grid + XCD-chunked swizzle (grid must be divisible by 8).
// EPI 0: f32. EPI 1: gelu(acc+bias)->bf16. EPI 2: acc+bias+add1+add2->f32. EPI 3: bf16.
template <int EPI>
__global__ __launch_bounds__(256) void gemm_bt(
    const unsigned short* __restrict__ A, const unsigned short* __restrict__ B,
    int M, int N, int K, int nbx,
    float* __restrict__ outF, unsigned short* __restrict__ outH,
    const float* __restrict__ bias, const float* __restrict__ add1,
    const float* __restrict__ add2) {
    __shared__ __align__(16) unsigned short As[128 * 32];
    __shared__ __align__(16) unsigned short Bs[128 * 32];
    int t = threadIdx.x, lane = t & 63, w = t >> 6;
    int nwg = gridDim.x;
    int cpx = nwg >> 3;
    int logical = (blockIdx.x & 7) * cpx + (blockIdx.x >> 3);
    int bx = logical % nbx, by = logical / nbx;
    int brow = by * 128, bcol = bx * 128;
    int wr = w >> 1, wc = w & 1;

    // staging: wave w owns segments 2w, 2w+1 (16 rows each) of As and Bs
    int lrow = lane >> 2, lk8 = (lane & 3) << 3;
    int seg0 = w * 2, seg1 = w * 2 + 1;
    const unsigned short* ga0 = A + (size_t)(brow + seg0 * 16 + lrow) * K + lk8;
    const unsigned short* ga1 = A + (size_t)(brow + seg1 * 16 + lrow) * K + lk8;
    int br0 = bcol + seg0 * 16 + lrow; if (br0 > N - 1) br0 = N - 1;
    int br1 = bcol + seg1 * 16 + lrow; if (br1 > N - 1) br1 = N - 1;
    const unsigned short* gb0 = B + (size_t)br0 * K + lk8;
    const unsigned short* gb1 = B + (size_t)br1 * K + lk8;
    unsigned short* la0 = &As[seg0 * 512];
    unsigned short* la1 = &As[seg1 * 512];
    unsigned short* lb0 = &Bs[seg0 * 512];
    unsigned short* lb1 = &Bs[seg1 * 512];

    f32x4 acc[4][4] = {};
    int lr = lane & 15, kk = (lane >> 4) << 3;
    for (int k0 = 0; k0 < K; k0 += 32) {
        gll16(ga0, la0); gll16(ga1, la1);
        gll16(gb0, lb0); gll16(gb1, lb1);
        ga0 += 32; ga1 += 32; gb0 += 32; gb1 += 32;
        __syncthreads();
        short8 af[4], bfr[4];
        #pragma unroll
        for (int f = 0; f < 4; ++f) {
            af[f]  = *(const short8*)&As[(wr * 64 + f * 16 + lr) * 32 + kk];
            bfr[f] = *(const short8*)&Bs[(wc * 64 + f * 16 + lr) * 32 + kk];
        }
        #pragma unroll
        for (int fm = 0; fm < 4; ++fm)
            #pragma unroll
            for (int fn = 0; fn < 4; ++fn)
                acc[fm][fn] = __builtin_amdgcn_mfma_f32_16x16x32_bf16(af[fm], bfr[fn], acc[fm][fn], 0, 0, 0);
        __syncthreads();
    }
    int rb = brow + wr * 64, cb = bcol + wc * 64;
    int rlane = (lane >> 4) << 2, clane = lane & 15;
    #pragma unroll
    for (int fm = 0; fm < 4; ++fm) {
        #pragma unroll
        for (int fn = 0; fn < 4; ++fn) {
            int col = cb + fn * 16 + clane;
            if (col < N) {
                #pragma unroll
                for (int j = 0; j < 4; ++j) {
                    int row = rb + fm * 16 + rlane + j;
                    size_t idx = (size_t)row * N + col;
                    float v = acc[fm][fn][j];
                    if constexpr (EPI == 0) {
                        outF[idx] = v;
                    } else if constexpr (EPI == 1) {
                        v += bias[col];
                        float g = 0.5f * v * (1.f + tanhf(0.7978845608f * (v + 0.044715f * v * v * v)));
                        outH[idx] = f2bf(g);
                    } else if constexpr (EPI == 2) {
                        outF[idx] = v + bias[col] + add1[idx] + add2[idx];
                    } else {
                        outH[idx] = f2bf(v);
                    }
                }
            }
        }
    }
}

// ---------------- dt: softplus + dt*A precompute ----------------
__global__ __launch_bounds__(256) void dtk(const unsigned short* __restrict__ zx,
                                           const float* __restrict__ dt_bias,
                                           const float* __restrict__ A_log,
                                           float* __restrict__ dtv, float* __restrict__ dtA) {
    int idx = blockIdx.x * 256 + threadIdx.x;   // < ROWS*NHEADS
    int h = idx & 63;
    size_t row = idx >> 6;
    float raw = bf2f(zx[row * DINPROJ + 10240 + h]) + dt_bias[h];
    float dt = raw > 20.f ? raw : log1pf(expf(raw));
    dtv[idx] = dt;
    dtA[idx] = dt * (-expf(A_log[h]));
}

// 64x64x64 bf16 MFMA: out rows = rows of Al, out cols = rows of Bl, K = inner 64.
static __device__ __forceinline__ void mm64(const unsigned short* Al, const unsigned short* Bl,
                                            f32x4* acc, int w, int lane) {
    int lr = lane & 15, kg = (lane >> 4) << 3;
    #pragma unroll
    for (int ks = 0; ks < 2; ++ks) {
        short8 a = *(const short8*)&Al[(w * 16 + lr) * 64 + ks * 32 + kg];
        #pragma unroll
        for (int fn = 0; fn < 4; ++fn) {
            short8 bb = *(const short8*)&Bl[(fn * 16 + lr) * 64 + ks * 32 + kg];
            acc[fn] = __builtin_amdgcn_mfma_f32_16x16x32_bf16(a, bb, acc[fn], 0, 0, 0);
        }
    }
}

// ---------------- K1: per-(b,h,chunk) intra-chunk work ----------------
__global__ __launch_bounds__(256) void chunk_front(const unsigned short* __restrict__ zx,
                                                   const float* __restrict__ dtv,
                                                   const float* __restrict__ dtA,
                                                   float* __restrict__ pcum,
                                                   unsigned short* __restrict__ ybuf,
                                                   unsigned short* __restrict__ Sbuf) {
    __shared__ __align__(16) unsigned short Cs[64*64], Bsr[64*64], Btr[64*64],
                                            Xtr[64*64], Xw[64*64], Wsm[64*64];
    __shared__ float dts[64], clg[64];
    int t = threadIdx.x, lane = t & 63, w = t >> 6;
    int bid = blockIdx.x;
    int c = bid & 31, h = (bid >> 5) & 63, b = bid >> 11, g = h >> 2;
    int row0 = (b << 11) + (c << 6);

    if (t < 64) {
        dts[t] = dtv[(size_t)(row0 + t) * 64 + h];
        float v = dtA[(size_t)(row0 + t) * 64 + h];
        #pragma unroll
        for (int off = 1; off < 64; off <<= 1) {
            float o = __shfl_up(v, off);
            if (lane >= off) v += o;
        }
        clg[t] = v;
        pcum[(size_t)(row0 + t) * 64 + h] = expf(v);
    }
    ushort4 xr[4];
    #pragma unroll
    for (int i = 0; i < 4; ++i) {
        int q = i * 256 + t, s = q >> 4, d4 = (q & 15) << 2;
        const unsigned short* rp = zx + (size_t)(row0 + s) * DINPROJ;
        ushort4 cv = *(const ushort4*)&rp[6144 + h * 64 + d4];
        *(ushort4*)&Cs[s * 64 + d4] = cv;
        ushort4 bv = *(const ushort4*)&rp[5120 + g * 64 + d4];
        *(ushort4*)&Bsr[s * 64 + d4] = bv;
        Btr[(d4 + 0) * 64 + s] = bv.x; Btr[(d4 + 1) * 64 + s] = bv.y;
        Btr[(d4 + 2) * 64 + s] = bv.z; Btr[(d4 + 3) * 64 + s] = bv.w;
        ushort4 xv = *(const ushort4*)&rp[4096 + g * 64 + d4];
        Xtr[(d4 + 0) * 64 + s] = xv.x; Xtr[(d4 + 1) * 64 + s] = xv.y;
        Xtr[(d4 + 2) * 64 + s] = xv.z; Xtr[(d4 + 3) * 64 + s] = xv.w;
        xr[i] = xv;
    }
    __syncthreads();
    float cl63 = clg[63];
    #pragma unroll
    for (int i = 0; i < 4; ++i) {
        int q = i * 256 + t, s = q >> 4, d4 = (q & 15) << 2;
        float ws = dts[s] * expf(cl63 - clg[s]);
        Xw[(d4 + 0) * 64 + s] = f2bf(bf2f(xr[i].x) * ws);
        Xw[(d4 + 1) * 64 + s] = f2bf(bf2f(xr[i].y) * ws);
        Xw[(d4 + 2) * 64 + s] = f2bf(bf2f(xr[i].z) * ws);
        Xw[(d4 + 3) * 64 + s] = f2bf(bf2f(xr[i].w) * ws);
    }
    __syncthreads();
    f32x4 accG[4] = {};
    mm64(Cs, Bsr, accG, w, lane);
    int rl = (lane >> 4) << 2, cl = lane & 15;
    #pragma unroll
    for (int fn = 0; fn < 4; ++fn) {
        #pragma unroll
        for (int j = 0; j < 4; ++j) {
            int tr = w * 16 + rl + j, rc = fn * 16 + cl;
            float val = 0.f;
            if (rc <= tr) val = accG[fn][j] * expf(clg[tr] - clg[rc]) * dts[rc];
            Wsm[tr * 64 + rc] = f2bf(val);
        }
    }
    __syncthreads();
    f32x4 accY[4] = {};
    mm64(Wsm, Xtr, accY, w, lane);
    f32x4 accS[4] = {};
    mm64(Xw, Btr, accS, w, lane);
    size_t cb = (size_t)((((b << 6) + h) << 5) + c) * 4096;
    #pragma unroll
    for (int fn = 0; fn < 4; ++fn) {
        #pragma unroll
        for (int j = 0; j < 4; ++j) {
            int tr = w * 16 + rl + j, pc = fn * 16 + cl;
            ybuf[(size_t)(row0 + tr) * DINNER + h * 64 + pc] = f2bf(accY[fn][j]);
            Sbuf[cb + tr * 64 + pc] = f2bf(accS[fn][j]);
        }
    }
}

// ---------------- K2: inter-chunk state recurrence (in-place S -> H0) ----------------
__global__ __launch_bounds__(256) void chunk_state(unsigned short* __restrict__ SH,
                                                   const float* __restrict__ pcum) {
    int b = blockIdx.x >> 6, h = blockIdx.x & 63, t = threadIdx.x;
    float H[16];
    #pragma unroll
    for (int j = 0; j < 16; ++j) H[j] = 0.f;
    for (int c = 0; c < NC; ++c) {
        size_t base = (size_t)((((b << 6) + h) << 5) + c) * 4096;
        float Tc = pcum[(size_t)((b << 11) + (c << 6) + 63) * 64 + h];
        #pragma unroll
        for (int j = 0; j < 16; ++j) {
            int e = j * 256 + t;
            unsigned short sv = SH[base + e];
            SH[base + e] = f2bf(H[j]);
            H[j] = H[j] * Tc + bf2f(sv);
        }
    }
}

// ---------------- K3: y += p_t * (C_t . H0) + Dp * x ----------------
__global__ __launch_bounds__(256) void chunk_back(const unsigned short* __restrict__ zx,
                                                  const unsigned short* __restrict__ SH,
                                                  const float* __restrict__ pcum,
                                                  const float* __restrict__ Dp,
                                                  unsigned short* __restrict__ ybuf) {
    __shared__ __align__(16) unsigned short Cs[64*64], Hs[64*64];
    __shared__ float ps[64];
    int t = threadIdx.x, lane = t & 63, w = t >> 6;
    int bid = blockIdx.x;
    int c = bid & 31, h = (bid >> 5) & 63, b = bid >> 11, g = h >> 2;
    int row0 = (b << 11) + (c << 6);
    size_t cb = (size_t)((((b << 6) + h) << 5) + c) * 4096;
    #pragma unroll
    for (int i = 0; i < 4; ++i) {
        int q = i * 256 + t, s = q >> 4, d4 = (q & 15) << 2;
        *(ushort4*)&Cs[s * 64 + d4] =
            *(const ushort4*)&zx[(size_t)(row0 + s) * DINPROJ + 6144 + h * 64 + d4];
        *(ushort4*)&Hs[s * 64 + d4] = *(const ushort4*)&SH[cb + s * 64 + d4];
    }
    if (t < 64) ps[t] = pcum[(size_t)(row0 + t) * 64 + h];
    __syncthreads();
    f32x4 acc[4] = {};
    mm64(Cs, Hs, acc, w, lane);
    float Dph = Dp[h];
    int rl = (lane >> 4) << 2, cl = lane & 15;
    #pragma unroll
    for (int fn = 0; fn < 4; ++fn) {
        #pragma unroll
        for (int j = 0; j < 4; ++j) {
            int tr = w * 16 + rl + j, pc = fn * 16 + cl;
            size_t yi = (size_t)(row0 + tr) * DINNER + h * 64 + pc;
            float xv = bf2f(zx[(size_t)(row0 + tr) * DINPROJ + 4096 + g * 64 + pc]);
            ybuf[yi] = f2bf(bf2f(ybuf[yi]) + acc[fn][j] * ps[tr] + Dph * xv);
        }
    }
}

// ---------------- gate (silu) + RMSNorm -> bf16 yf ----------------
__global__ __launch_bounds__(256) void gate_kernel(const unsigned short* __restrict__ y,
                                                   const unsigned short* __restrict__ zx,
                                                   const float* __restrict__ norm_w,
                                                   unsigned short* __restrict__ yf) {
    int row = blockIdx.x;
    int t = threadIdx.x;
    float v[16];
    float s2 = 0.f;
    #pragma unroll
    for (int i = 0; i < 16; ++i) {
        int d = i * 256 + t;
        float yv = bf2f(y[(size_t)row * DINNER + d]);
        float zv = bf2f(zx[(size_t)row * DINPROJ + d]);
        float gt = zv / (1.f + expf(-zv));
        v[i] = yv * gt;
        s2 += v[i] * v[i];
    }
    #pragma unroll
    for (int off = 1; off < 64; off <<= 1) s2 += __shfl_xor(s2, off);
    __shared__ float sb[4];
    int lane = t & 63, wv = t >> 6;
    if (lane == 0) sb[wv] = s2;
    __syncthreads();
    s2 = sb[0] + sb[1] + sb[2] + sb[3];
    float sc = rsqrtf(s2 / DINNER + EPSV);
    #pragma unroll
    for (int i = 0; i < 16; ++i) {
        int d = i * 256 + t;
        yf[(size_t)row * DINNER + d] = f2bf(v[i] * sc * norm_w[d]);
    }
}

extern "C" void kernel_launch(void* const* d_in, const int* in_sizes, int n_in,
                              void* d_out, int out_size, void* d_ws, size_t ws_size,
                              hipStream_t stream) {
    const float* hid   = (const float*)d_in[0];
    const float* ln_w  = (const float*)d_in[1];
    const float* ln_b  = (const float*)d_in[2];
    const float* w_inp = (const float*)d_in[3];
    const float* dtb   = (const float*)d_in[4];
    const float* A_log = (const float*)d_in[5];
    const float* Dp    = (const float*)d_in[6];
    const float* nw    = (const float*)d_in[7];
    const float* w_out = (const float*)d_in[8];
    const float* w_fc1 = (const float*)d_in[9];
    const float* fc1_b = (const float*)d_in[10];
    const float* w_fc2 = (const float*)d_in[11];
    const float* fc2_b = (const float*)d_in[12];

    char* ws = (char*)d_ws;
    size_t off = 0;
    auto alloc = [&](size_t bytes) { size_t o = off; off += (bytes + 255) & ~(size_t)255; return o; };
    size_t o_h    = alloc((size_t)ROWS * DMODEL * 2);        // h bf16
    size_t o_w    = alloc((size_t)DINPROJ * DMODEL * 2);     // shared weight bf16 buffer
    size_t o_zx   = alloc((size_t)ROWS * DINPROJ * 2);       // zxbcdt bf16 (later: gelu bf16)
    size_t o_dt   = alloc((size_t)ROWS * NHEADS * 4);        // dt f32
    size_t o_dta  = alloc((size_t)ROWS * NHEADS * 4);        // dt*A f32
    size_t o_pc   = alloc((size_t)ROWS * NHEADS * 4);        // pcum f32
    size_t o_y    = alloc((size_t)ROWS * DINNER * 2);        // y bf16 (later: mamba f32 area reuse)
    size_t o_yf   = alloc((size_t)ROWS * DINNER * 2);        // yf bf16
    size_t o_S    = alloc((size_t)BATCH * NHEADS * NC * HEADDIM * DSTATE * 2); // S->H0 bf16

    unsigned short* h_bf  = (unsigned short*)(ws + o_h);
    unsigned short* wbuf  = (unsigned short*)(ws + o_w);
    unsigned short* zx    = (unsigned short*)(ws + o_zx);
    float* dtv            = (float*)(ws + o_dt);
    float* dtA            = (float*)(ws + o_dta);
    float* pcum           = (float*)(ws + o_pc);
    unsigned short* ybuf  = (unsigned short*)(ws + o_y);
    unsigned short* yf    = (unsigned short*)(ws + o_yf);
    unsigned short* Sbuf  = (unsigned short*)(ws + o_S);
    unsigned short* gelu  = (unsigned short*)(ws + o_zx);    // alias: zx dead after gate
    float* mamba          = (float*)(ws + o_y);              // alias: y dead after gate
    float* outF           = (float*)d_out;

    // 1) LayerNorm -> h (bf16)
    ln_kernel<<<ROWS, 256, 0, stream>>>(hid, ln_w, ln_b, h_bf);
    // 2) in_proj GEMM -> zx (bf16)
    convk<<<2048, 256, 0, stream>>>(w_inp, wbuf, (DINPROJ * DMODEL) / 4);
    gemm_bt<3><<<81 * 32, 256, 0, stream>>>(
        h_bf, wbuf, ROWS, DINPROJ, DMODEL, 81, nullptr, zx, nullptr, nullptr, nullptr);
    // 3) dt softplus + dt*A
    dtk<<<(ROWS * NHEADS) / 256, 256, 0, stream>>>(zx, dtb, A_log, dtv, dtA);
    // 4) chunked SSD scan
    chunk_front<<<BATCH * NHEADS * NC, 256, 0, stream>>>(zx, dtv, dtA, pcum, ybuf, Sbuf);
    chunk_state<<<BATCH * NHEADS, 256, 0, stream>>>(Sbuf, pcum);
    chunk_back<<<BATCH * NHEADS * NC, 256, 0, stream>>>(zx, Sbuf, pcum, Dp, ybuf);
    // 5) gate + RMSNorm -> yf (bf16)
    gate_kernel<<<ROWS, 256, 0, stream>>>(ybuf, zx, nw, yf);
    // 6) out_proj GEMM -> mamba (f32)
    convk<<<2048, 256, 0, stream>>>(w_out, wbuf, (DMODEL * DINNER) / 4);
    gemm_bt<0><<<16 * 32, 256, 0, stream>>>(
        yf, wbuf, ROWS, DMODEL, DINNER, 16, mamba, nullptr, nullptr, nullptr, nullptr);
    // 7) fc1 GEMM + gelu -> gelu (bf16, aliases zx)
    convk<<<2048, 256, 0, stream>>>(w_fc1, wbuf, (INTER * DMODEL) / 4);
    gemm_bt<1><<<64 * 32, 256, 0, stream>>>(
        h_bf, wbuf, ROWS, INTER, DMODEL, 64, nullptr, gelu, fc1_b, nullptr, nullptr);
    // 8) fc2 GEMM + bias + mamba + residual -> d_out (f32)
    convk<<<2048, 256, 0, stream>>>(w_fc2, wbuf, (DMODEL * INTER) / 4);
    gemm_bt<2><<<16 * 32, 256, 0, stream>>>(
        gelu, wbuf, ROWS, DMODEL, INTER, 16, outF, nullptr, fc2_b, mamba, hid);
}

// Round 4
// 848.196 us; speedup vs baseline: 1.7393x; 1.2161x over previous
//
#include <hip/hip_runtime.h>
#include <hip/hip_bf16.h>

#define BATCH 2
#define SEQ   2048
#define DMODEL 2048
#define DINNER 4096
#define DXB   1024
#define NHEADS 64
#define NKV   16
#define HEADDIM 64
#define DSTATE 64
#define INTER 8192
#define DINPROJ 10304   // 4096 z + 1024 x + 1024 B + 4096 C + 64 dt
#define ROWS  (BATCH*SEQ)   // 4096
#define NC    32            // chunks per sequence
#define EPSV  1e-5f

typedef short short8 __attribute__((ext_vector_type(8)));
typedef float f32x4 __attribute__((ext_vector_type(4)));

typedef const __attribute__((address_space(1))) unsigned int cg_u32;
typedef __attribute__((address_space(3))) unsigned int ls_u32;

static __device__ __forceinline__ void gll16(const void* g, void* l) {
    __builtin_amdgcn_global_load_lds((cg_u32*)g, (ls_u32*)l, 16, 0, 0);
}

static __device__ __forceinline__ unsigned short f2bf(float f) {
    unsigned int u = __float_as_uint(f);
    unsigned int r = (u + 0x7fffu + ((u >> 16) & 1u)) >> 16;
    return (unsigned short)r;
}
static __device__ __forceinline__ float bf2f(unsigned short h) {
    return __uint_as_float(((unsigned int)h) << 16);
}

// ---------------- f32 -> bf16 conversion (grid-stride, float4) ----------------
__global__ __launch_bounds__(256) void convk(const float* __restrict__ in,
                                             unsigned short* __restrict__ out, int n4) {
    int stride = gridDim.x * blockDim.x;
    for (int i = blockIdx.x * blockDim.x + threadIdx.x; i < n4; i += stride) {
        float4 v = ((const float4*)in)[i];
        ushort4 o;
        o.x = f2bf(v.x); o.y = f2bf(v.y); o.z = f2bf(v.z); o.w = f2bf(v.w);
        ((ushort4*)out)[i] = o;
    }
}

// ---------------- LayerNorm: one block per row, writes bf16 h ----------------
__global__ __launch_bounds__(256) void ln_kernel(const float* __restrict__ x,
                                                 const float* __restrict__ w,
                                                 const float* __restrict__ b,
                                                 unsigned short* __restrict__ hout) {
    int row = blockIdx.x;
    int t = threadIdx.x;
    const float* xr = x + (size_t)row * DMODEL;
    float v[8];
    float4 v0 = *(const float4*)&xr[t * 8];
    float4 v1 = *(const float4*)&xr[t * 8 + 4];
    v[0]=v0.x; v[1]=v0.y; v[2]=v0.z; v[3]=v0.w; v[4]=v1.x; v[5]=v1.y; v[6]=v1.z; v[7]=v1.w;
    float s = 0.f, s2 = 0.f;
    #pragma unroll
    for (int i = 0; i < 8; ++i) { s += v[i]; s2 += v[i]*v[i]; }
    #pragma unroll
    for (int off = 1; off < 64; off <<= 1) { s += __shfl_xor(s, off); s2 += __shfl_xor(s2, off); }
    __shared__ float sa[4], sb[4];
    int lane = t & 63, wv = t >> 6;
    if (lane == 0) { sa[wv] = s; sb[wv] = s2; }
    __syncthreads();
    s = sa[0]+sa[1]+sa[2]+sa[3];
    s2 = sb[0]+sb[1]+sb[2]+sb[3];
    float mu = s / DMODEL;
    float var = s2 / DMODEL - mu * mu;
    float sc = rsqrtf(var + EPSV);
    unsigned short* ho = hout + (size_t)row * DMODEL + t * 8;
    #pragma unroll
    for (int i = 0; i < 8; ++i) {
        int d = t * 8 + i;
        ho[i] = f2bf((v[i] - mu) * sc * w[d] + b[d]);
    }
}

// ---------------- pipelined bf16 MFMA GEMM: C[M,N] = A[M,K] * B[N,K]^T ----------
// 128x256 tile, BK=64, 8 waves (2x4), ring-3 LDS (144KB), global_load_lds staging
// with pre-swizzled global source (T2), counted vmcnt(6) + 1 barrier per K-tile
// (T4), setprio around MFMA clusters (T5), XCD-chunked block swizzle (T1).
// EPI 0: f32. EPI 1: gelu(acc+bias)->bf16. EPI 2: acc+bias+add1+add2->f32. EPI 3: bf16.
#define SLOTSZ 49152
template <int EPI>
__global__ __launch_bounds__(512, 2) void gemm_p(
    const unsigned short* __restrict__ A, const unsigned short* __restrict__ B,
    int M, int N, int K, int nbx,
    float* __restrict__ outF, unsigned short* __restrict__ outH,
    const float* __restrict__ bias, const float* __restrict__ add1,
    const float* __restrict__ add2) {
    __shared__ __align__(16) char smem[3 * SLOTSZ];
    int t = threadIdx.x, lane = t & 63, w = t >> 6;
    int nwg = gridDim.x, cpx = nwg >> 3;
    int logical = (blockIdx.x & 7) * cpx + (blockIdx.x >> 3);
    int bx = logical % nbx, by = logical / nbx;
    int brow = by * 128, bcol = bx * 256;
    int wr = w >> 2, wc = w & 3;
    int wrb = wr * 64, wcb = wc * 64;

    // staging source (swizzled): lane l fetches row (l>>3), chunk (l&7)^(l>>3)
    int lr8 = lane >> 3;
    int lch = ((lane & 7) ^ lr8) << 3;          // element offset within 64-elem row
    const unsigned short* pa[2];
    #pragma unroll
    for (int j = 0; j < 2; ++j)
        pa[j] = A + (size_t)(brow + w * 16 + j * 8 + lr8) * K + lch;
    const unsigned short* pb[4];
    #pragma unroll
    for (int j = 0; j < 4; ++j) {
        int r = bcol + w * 32 + j * 8 + lr8;
        if (r > N - 1) r = N - 1;
        pb[j] = B + (size_t)r * K + lch;
    }
    auto stageA = [&](int slot, int j) {
        gll16(pa[j], smem + slot * SLOTSZ + (w * 16 + j * 8) * 128);
        pa[j] += 64;
    };
    auto stageB = [&](int slot, int j) {
        gll16(pb[j], smem + slot * SLOTSZ + 16384 + (w * 32 + j * 8) * 128);
        pb[j] += 64;
    };

    // fragment-read swizzle: byte = row*128 + ((c ^ (row&7))*16), c = ks*4 + (lane>>4)
    int arow = lane & 15;
    int swz0 = (((lane >> 4) ^ (lane & 7)) << 4);

    f32x4 acc[4][4] = {};
    const int NT = K >> 6;
    #pragma unroll
    for (int j = 0; j < 2; ++j) stageA(0, j);
    #pragma unroll
    for (int j = 0; j < 4; ++j) stageB(0, j);
    #pragma unroll
    for (int j = 0; j < 2; ++j) stageA(1, j);
    #pragma unroll
    for (int j = 0; j < 4; ++j) stageB(1, j);

    int slot = 0, slot2 = 2;
    for (int kt = 0; kt < NT; ++kt) {
        if (kt + 1 < NT) { asm volatile("s_waitcnt vmcnt(6)" ::: "memory"); }
        else             { asm volatile("s_waitcnt vmcnt(0)" ::: "memory"); }
        __builtin_amdgcn_s_barrier();
        asm volatile("" ::: "memory");
        const char* Ab = smem + slot * SLOTSZ;
        const char* Bb = Ab + 16384;
        bool st = (kt + 2 < NT);
        // ---- phase 0 (k 0..31) ----
        short8 af[4], bfv[4];
        #pragma unroll
        for (int f = 0; f < 4; ++f)
            af[f] = *(const short8*)(Ab + (wrb + f * 16 + arow) * 128 + swz0);
        #pragma unroll
        for (int n = 0; n < 4; ++n)
            bfv[n] = *(const short8*)(Bb + (wcb + n * 16 + arow) * 128 + swz0);
        if (st) { stageA(slot2, 0); stageA(slot2, 1); stageB(slot2, 0); }
        __builtin_amdgcn_s_setprio(1);
        #pragma unroll
        for (int f = 0; f < 4; ++f)
            #pragma unroll
            for (int n = 0; n < 4; ++n)
                acc[f][n] = __builtin_amdgcn_mfma_f32_16x16x32_bf16(af[f], bfv[n], acc[f][n], 0, 0, 0);
        __builtin_amdgcn_s_setprio(0);
        // ---- phase 1 (k 32..63) ----
        #pragma unroll
        for (int f = 0; f < 4; ++f)
            af[f] = *(const short8*)(Ab + (wrb + f * 16 + arow) * 128 + (swz0 ^ 64));
        #pragma unroll
        for (int n = 0; n < 4; ++n)
            bfv[n] = *(const short8*)(Bb + (wcb + n * 16 + arow) * 128 + (swz0 ^ 64));
        if (st) { stageB(slot2, 1); stageB(slot2, 2); stageB(slot2, 3); }
        __builtin_amdgcn_s_setprio(1);
        #pragma unroll
        for (int f = 0; f < 4; ++f)
            #pragma unroll
            for (int n = 0; n < 4; ++n)
                acc[f][n] = __builtin_amdgcn_mfma_f32_16x16x32_bf16(af[f], bfv[n], acc[f][n], 0, 0, 0);
        __builtin_amdgcn_s_setprio(0);
        slot  = (slot  == 2) ? 0 : slot + 1;
        slot2 = (slot2 == 2) ? 0 : slot2 + 1;
    }

    int rlane = (lane >> 4) << 2, clane = lane & 15;
    #pragma unroll
    for (int f = 0; f < 4; ++f) {
        #pragma unroll
        for (int n = 0; n < 4; ++n) {
            int col = bcol + wcb + n * 16 + clane;
            if (col < N) {
                #pragma unroll
                for (int j = 0; j < 4; ++j) {
                    int row = brow + wrb + f * 16 + rlane + j;
                    size_t idx = (size_t)row * N + col;
                    float v = acc[f][n][j];
                    if constexpr (EPI == 0) {
                        outF[idx] = v;
                    } else if constexpr (EPI == 1) {
                        v += bias[col];
                        float g = 0.5f * v * (1.f + tanhf(0.7978845608f * (v + 0.044715f * v * v * v)));
                        outH[idx] = f2bf(g);
                    } else if constexpr (EPI == 2) {
                        outF[idx] = v + bias[col] + add1[idx] + add2[idx];
                    } else {
                        outH[idx] = f2bf(v);
                    }
                }
            }
        }
    }
}

// ---------------- dt: softplus + dt*A precompute ----------------
__global__ __launch_bounds__(256) void dtk(const unsigned short* __restrict__ zx,
                                           const float* __restrict__ dt_bias,
                                           const float* __restrict__ A_log,
                                           float* __restrict__ dtv, float* __restrict__ dtA) {
    int idx = blockIdx.x * 256 + threadIdx.x;   // < ROWS*NHEADS
    int h = idx & 63;
    size_t row = idx >> 6;
    float raw = bf2f(zx[row * DINPROJ + 10240 + h]) + dt_bias[h];
    float dt = raw > 20.f ? raw : log1pf(expf(raw));
    dtv[idx] = dt;
    dtA[idx] = dt * (-expf(A_log[h]));
}

// 64x64x64 bf16 MFMA: out rows = rows of Al, out cols = rows of Bl, K = inner 64.
static __device__ __forceinline__ void mm64(const unsigned short* Al, const unsigned short* Bl,
                                            f32x4* acc, int w, int lane) {
    int lr = lane & 15, kg = (lane >> 4) << 3;
    #pragma unroll
    for (int ks = 0; ks < 2; ++ks) {
        short8 a = *(const short8*)&Al[(w * 16 + lr) * 64 + ks * 32 + kg];
        #pragma unroll
        for (int fn = 0; fn < 4; ++fn) {
            short8 bb = *(const short8*)&Bl[(fn * 16 + lr) * 64 + ks * 32 + kg];
            acc[fn] = __builtin_amdgcn_mfma_f32_16x16x32_bf16(a, bb, acc[fn], 0, 0, 0);
        }
    }
}

// ---------------- K1: per-(b,h,chunk) intra-chunk work ----------------
__global__ __launch_bounds__(256) void chunk_front(const unsigned short* __restrict__ zx,
                                                   const float* __restrict__ dtv,
                                                   const float* __restrict__ dtA,
                                                   float* __restrict__ pcum,
                                                   unsigned short* __restrict__ ybuf,
                                                   unsigned short* __restrict__ Sbuf) {
    __shared__ __align__(16) unsigned short Cs[64*64], Bsr[64*64], Btr[64*64],
                                            Xtr[64*64], Xw[64*64], Wsm[64*64];
    __shared__ float dts[64], clg[64];
    int t = threadIdx.x, lane = t & 63, w = t >> 6;
    int bid = blockIdx.x;
    int c = bid & 31, h = (bid >> 5) & 63, b = bid >> 11, g = h >> 2;
    int row0 = (b << 11) + (c << 6);

    if (t < 64) {
        dts[t] = dtv[(size_t)(row0 + t) * 64 + h];
        float v = dtA[(size_t)(row0 + t) * 64 + h];
        #pragma unroll
        for (int off = 1; off < 64; off <<= 1) {
            float o = __shfl_up(v, off);
            if (lane >= off) v += o;
        }
        clg[t] = v;
        pcum[(size_t)(row0 + t) * 64 + h] = expf(v);
    }
    ushort4 xr[4];
    #pragma unroll
    for (int i = 0; i < 4; ++i) {
        int q = i * 256 + t, s = q >> 4, d4 = (q & 15) << 2;
        const unsigned short* rp = zx + (size_t)(row0 + s) * DINPROJ;
        ushort4 cv = *(const ushort4*)&rp[6144 + h * 64 + d4];
        *(ushort4*)&Cs[s * 64 + d4] = cv;
        ushort4 bv = *(const ushort4*)&rp[5120 + g * 64 + d4];
        *(ushort4*)&Bsr[s * 64 + d4] = bv;
        Btr[(d4 + 0) * 64 + s] = bv.x; Btr[(d4 + 1) * 64 + s] = bv.y;
        Btr[(d4 + 2) * 64 + s] = bv.z; Btr[(d4 + 3) * 64 + s] = bv.w;
        ushort4 xv = *(const ushort4*)&rp[4096 + g * 64 + d4];
        Xtr[(d4 + 0) * 64 + s] = xv.x; Xtr[(d4 + 1) * 64 + s] = xv.y;
        Xtr[(d4 + 2) * 64 + s] = xv.z; Xtr[(d4 + 3) * 64 + s] = xv.w;
        xr[i] = xv;
    }
    __syncthreads();
    float cl63 = clg[63];
    #pragma unroll
    for (int i = 0; i < 4; ++i) {
        int q = i * 256 + t, s = q >> 4, d4 = (q & 15) << 2;
        float ws = dts[s] * expf(cl63 - clg[s]);
        Xw[(d4 + 0) * 64 + s] = f2bf(bf2f(xr[i].x) * ws);
        Xw[(d4 + 1) * 64 + s] = f2bf(bf2f(xr[i].y) * ws);
        Xw[(d4 + 2) * 64 + s] = f2bf(bf2f(xr[i].z) * ws);
        Xw[(d4 + 3) * 64 + s] = f2bf(bf2f(xr[i].w) * ws);
    }
    __syncthreads();
    f32x4 accG[4] = {};
    mm64(Cs, Bsr, accG, w, lane);
    int rl = (lane >> 4) << 2, cl = lane & 15;
    #pragma unroll
    for (int fn = 0; fn < 4; ++fn) {
        #pragma unroll
        for (int j = 0; j < 4; ++j) {
            int tr = w * 16 + rl + j, rc = fn * 16 + cl;
            float val = 0.f;
            if (rc <= tr) val = accG[fn][j] * expf(clg[tr] - clg[rc]) * dts[rc];
            Wsm[tr * 64 + rc] = f2bf(val);
        }
    }
    __syncthreads();
    f32x4 accY[4] = {};
    mm64(Wsm, Xtr, accY, w, lane);
    f32x4 accS[4] = {};
    mm64(Xw, Btr, accS, w, lane);
    size_t cb = (size_t)((((b << 6) + h) << 5) + c) * 4096;
    #pragma unroll
    for (int fn = 0; fn < 4; ++fn) {
        #pragma unroll
        for (int j = 0; j < 4; ++j) {
            int tr = w * 16 + rl + j, pc = fn * 16 + cl;
            ybuf[(size_t)(row0 + tr) * DINNER + h * 64 + pc] = f2bf(accY[fn][j]);
            Sbuf[cb + tr * 64 + pc] = f2bf(accS[fn][j]);
        }
    }
}

// ---------------- K2: inter-chunk state recurrence (in-place S -> H0) ----------------
__global__ __launch_bounds__(256) void chunk_state(unsigned short* __restrict__ SH,
                                                   const float* __restrict__ pcum) {
    int b = blockIdx.x >> 6, h = blockIdx.x & 63, t = threadIdx.x;
    float H[16];
    #pragma unroll
    for (int j = 0; j < 16; ++j) H[j] = 0.f;
    for (int c = 0; c < NC; ++c) {
        size_t base = (size_t)((((b << 6) + h) << 5) + c) * 4096;
        float Tc = pcum[(size_t)((b << 11) + (c << 6) + 63) * 64 + h];
        #pragma unroll
        for (int j = 0; j < 16; ++j) {
            int e = j * 256 + t;
            unsigned short sv = SH[base + e];
            SH[base + e] = f2bf(H[j]);
            H[j] = H[j] * Tc + bf2f(sv);
        }
    }
}

// ---------------- K3: y += p_t * (C_t . H0) + Dp * x ----------------
__global__ __launch_bounds__(256) void chunk_back(const unsigned short* __restrict__ zx,
                                                  const unsigned short* __restrict__ SH,
                                                  const float* __restrict__ pcum,
                                                  const float* __restrict__ Dp,
                                                  unsigned short* __restrict__ ybuf) {
    __shared__ __align__(16) unsigned short Cs[64*64], Hs[64*64];
    __shared__ float ps[64];
    int t = threadIdx.x, lane = t & 63, w = t >> 6;
    int bid = blockIdx.x;
    int c = bid & 31, h = (bid >> 5) & 63, b = bid >> 11, g = h >> 2;
    int row0 = (b << 11) + (c << 6);
    size_t cb = (size_t)((((b << 6) + h) << 5) + c) * 4096;
    #pragma unroll
    for (int i = 0; i < 4; ++i) {
        int q = i * 256 + t, s = q >> 4, d4 = (q & 15) << 2;
        *(ushort4*)&Cs[s * 64 + d4] =
            *(const ushort4*)&zx[(size_t)(row0 + s) * DINPROJ + 6144 + h * 64 + d4];
        *(ushort4*)&Hs[s * 64 + d4] = *(const ushort4*)&SH[cb + s * 64 + d4];
    }
    if (t < 64) ps[t] = pcum[(size_t)(row0 + t) * 64 + h];
    __syncthreads();
    f32x4 acc[4] = {};
    mm64(Cs, Hs, acc, w, lane);
    float Dph = Dp[h];
    int rl = (lane >> 4) << 2, cl = lane & 15;
    #pragma unroll
    for (int fn = 0; fn < 4; ++fn) {
        #pragma unroll
        for (int j = 0; j < 4; ++j) {
            int tr = w * 16 + rl + j, pc = fn * 16 + cl;
            size_t yi = (size_t)(row0 + tr) * DINNER + h * 64 + pc;
            float xv = bf2f(zx[(size_t)(row0 + tr) * DINPROJ + 4096 + g * 64 + pc]);
            ybuf[yi] = f2bf(bf2f(ybuf[yi]) + acc[fn][j] * ps[tr] + Dph * xv);
        }
    }
}

// ---------------- gate (silu) + RMSNorm -> bf16 yf ----------------
__global__ __launch_bounds__(256) void gate_kernel(const unsigned short* __restrict__ y,
                                                   const unsigned short* __restrict__ zx,
                                                   const float* __restrict__ norm_w,
                                                   unsigned short* __restrict__ yf) {
    int row = blockIdx.x;
    int t = threadIdx.x;
    float v[16];
    float s2 = 0.f;
    #pragma unroll
    for (int i = 0; i < 16; ++i) {
        int d = i * 256 + t;
        float yv = bf2f(y[(size_t)row * DINNER + d]);
        float zv = bf2f(zx[(size_t)row * DINPROJ + d]);
        float gt = zv / (1.f + expf(-zv));
        v[i] = yv * gt;
        s2 += v[i] * v[i];
    }
    #pragma unroll
    for (int off = 1; off < 64; off <<= 1) s2 += __shfl_xor(s2, off);
    __shared__ float sb[4];
    int lane = t & 63, wv = t >> 6;
    if (lane == 0) sb[wv] = s2;
    __syncthreads();
    s2 = sb[0] + sb[1] + sb[2] + sb[3];
    float sc = rsqrtf(s2 / DINNER + EPSV);
    #pragma unroll
    for (int i = 0; i < 16; ++i) {
        int d = i * 256 + t;
        yf[(size_t)row * DINNER + d] = f2bf(v[i] * sc * norm_w[d]);
    }
}

extern "C" void kernel_launch(void* const* d_in, const int* in_sizes, int n_in,
                              void* d_out, int out_size, void* d_ws, size_t ws_size,
                              hipStream_t stream) {
    const float* hid   = (const float*)d_in[0];
    const float* ln_w  = (const float*)d_in[1];
    const float* ln_b  = (const float*)d_in[2];
    const float* w_inp = (const float*)d_in[3];
    const float* dtb   = (const float*)d_in[4];
    const float* A_log = (const float*)d_in[5];
    const float* Dp    = (const float*)d_in[6];
    const float* nw    = (const float*)d_in[7];
    const float* w_out = (const float*)d_in[8];
    const float* w_fc1 = (const float*)d_in[9];
    const float* fc1_b = (const float*)d_in[10];
    const float* w_fc2 = (const float*)d_in[11];
    const float* fc2_b = (const float*)d_in[12];

    char* ws = (char*)d_ws;
    size_t off = 0;
    auto alloc = [&](size_t bytes) { size_t o = off; off += (bytes + 255) & ~(size_t)255; return o; };
    size_t o_h    = alloc((size_t)ROWS * DMODEL * 2);        // h bf16
    size_t o_w    = alloc((size_t)DINPROJ * DMODEL * 2);     // shared weight bf16 buffer
    size_t o_zx   = alloc((size_t)ROWS * DINPROJ * 2);       // zxbcdt bf16 (later: gelu bf16)
    size_t o_dt   = alloc((size_t)ROWS * NHEADS * 4);        // dt f32
    size_t o_dta  = alloc((size_t)ROWS * NHEADS * 4);        // dt*A f32
    size_t o_pc   = alloc((size_t)ROWS * NHEADS * 4);        // pcum f32
    size_t o_y    = alloc((size_t)ROWS * DINNER * 2);        // y bf16 (later: mamba f32 area reuse)
    size_t o_yf   = alloc((size_t)ROWS * DINNER * 2);        // yf bf16
    size_t o_S    = alloc((size_t)BATCH * NHEADS * NC * HEADDIM * DSTATE * 2); // S->H0 bf16

    unsigned short* h_bf  = (unsigned short*)(ws + o_h);
    unsigned short* wbuf  = (unsigned short*)(ws + o_w);
    unsigned short* zx    = (unsigned short*)(ws + o_zx);
    float* dtv            = (float*)(ws + o_dt);
    float* dtA            = (float*)(ws + o_dta);
    float* pcum           = (float*)(ws + o_pc);
    unsigned short* ybuf  = (unsigned short*)(ws + o_y);
    unsigned short* yf    = (unsigned short*)(ws + o_yf);
    unsigned short* Sbuf  = (unsigned short*)(ws + o_S);
    unsigned short* gelu  = (unsigned short*)(ws + o_zx);    // alias: zx dead after gate
    float* mamba          = (float*)(ws + o_y);              // alias: y dead after gate
    float* outF           = (float*)d_out;

    // 1) LayerNorm -> h (bf16)
    ln_kernel<<<ROWS, 256, 0, stream>>>(hid, ln_w, ln_b, h_bf);
    // 2) in_proj GEMM -> zx (bf16); N-tiles = ceil(10304/256) = 41
    convk<<<2048, 256, 0, stream>>>(w_inp, wbuf, (DINPROJ * DMODEL) / 4);
    gemm_p<3><<<41 * 32, 512, 0, stream>>>(
        h_bf, wbuf, ROWS, DINPROJ, DMODEL, 41, nullptr, zx, nullptr, nullptr, nullptr);
    // 3) dt softplus + dt*A
    dtk<<<(ROWS * NHEADS) / 256, 256, 0, stream>>>(zx, dtb, A_log, dtv, dtA);
    // 4) chunked SSD scan
    chunk_front<<<BATCH * NHEADS * NC, 256, 0, stream>>>(zx, dtv, dtA, pcum, ybuf, Sbuf);
    chunk_state<<<BATCH * NHEADS, 256, 0, stream>>>(Sbuf, pcum);
    chunk_back<<<BATCH * NHEADS * NC, 256, 0, stream>>>(zx, Sbuf, pcum, Dp, ybuf);
    // 5) gate + RMSNorm -> yf (bf16)
    gate_kernel<<<ROWS, 256, 0, stream>>>(ybuf, zx, nw, yf);
    // 6) out_proj GEMM -> mamba (f32)
    convk<<<2048, 256, 0, stream>>>(w_out, wbuf, (DMODEL * DINNER) / 4);
    gemm_p<0><<<8 * 32, 512, 0, stream>>>(
        yf, wbuf, ROWS, DMODEL, DINNER, 8, mamba, nullptr, nullptr, nullptr, nullptr);
    // 7) fc1 GEMM + gelu -> gelu (bf16, aliases zx)
    convk<<<2048, 256, 0, stream>>>(w_fc1, wbuf, (INTER * DMODEL) / 4);
    gemm_p<1><<<32 * 32, 512, 0, stream>>>(
        h_bf, wbuf, ROWS, INTER, DMODEL, 32, nullptr, gelu, fc1_b, nullptr, nullptr);
    // 8) fc2 GEMM + bias + mamba + residual -> d_out (f32)
    convk<<<2048, 256, 0, stream>>>(w_fc2, wbuf, (DMODEL * INTER) / 4);
    gemm_p<2><<<8 * 32, 512, 0, stream>>>(
        gelu, wbuf, ROWS, DMODEL, INTER, 8, outF, nullptr, fc2_b, mamba, hid);
}

// Round 5
// 790.670 us; speedup vs baseline: 1.8658x; 1.0728x over previous
//
#include <hip/hip_runtime.h>
#include <hip/hip_bf16.h>

#define BATCH 2
#define SEQ   2048
#define DMODEL 2048
#define DINNER 4096
#define DXB   1024
#define NHEADS 64
#define NKV   16
#define HEADDIM 64
#define DSTATE 64
#define INTER 8192
#define DINPROJ 10304   // 4096 z + 1024 x + 1024 B + 4096 C + 64 dt
#define ROWS  (BATCH*SEQ)   // 4096
#define NC    32            // chunks per sequence
#define EPSV  1e-5f

typedef short short8 __attribute__((ext_vector_type(8)));
typedef float f32x4 __attribute__((ext_vector_type(4)));

typedef const __attribute__((address_space(1))) unsigned int cg_u32;
typedef __attribute__((address_space(3))) unsigned int ls_u32;

static __device__ __forceinline__ void gll16(const void* g, void* l) {
    __builtin_amdgcn_global_load_lds((cg_u32*)g, (ls_u32*)l, 16, 0, 0);
}

static __device__ __forceinline__ unsigned short f2bf(float f) {
    unsigned int u = __float_as_uint(f);
    unsigned int r = (u + 0x7fffu + ((u >> 16) & 1u)) >> 16;
    return (unsigned short)r;
}
static __device__ __forceinline__ float bf2f(unsigned short h) {
    return __uint_as_float(((unsigned int)h) << 16);
}

// ---------------- f32 -> bf16 conversion (grid-stride, float4) ----------------
__global__ __launch_bounds__(256) void convk(const float* __restrict__ in,
                                             unsigned short* __restrict__ out, int n4) {
    int stride = gridDim.x * blockDim.x;
    for (int i = blockIdx.x * blockDim.x + threadIdx.x; i < n4; i += stride) {
        float4 v = ((const float4*)in)[i];
        ushort4 o;
        o.x = f2bf(v.x); o.y = f2bf(v.y); o.z = f2bf(v.z); o.w = f2bf(v.w);
        ((ushort4*)out)[i] = o;
    }
}

// ---------------- LayerNorm: one block per row, writes bf16 h ----------------
__global__ __launch_bounds__(256) void ln_kernel(const float* __restrict__ x,
                                                 const float* __restrict__ w,
                                                 const float* __restrict__ b,
                                                 unsigned short* __restrict__ hout) {
    int row = blockIdx.x;
    int t = threadIdx.x;
    const float* xr = x + (size_t)row * DMODEL;
    float v[8];
    float4 v0 = *(const float4*)&xr[t * 8];
    float4 v1 = *(const float4*)&xr[t * 8 + 4];
    v[0]=v0.x; v[1]=v0.y; v[2]=v0.z; v[3]=v0.w; v[4]=v1.x; v[5]=v1.y; v[6]=v1.z; v[7]=v1.w;
    float s = 0.f, s2 = 0.f;
    #pragma unroll
    for (int i = 0; i < 8; ++i) { s += v[i]; s2 += v[i]*v[i]; }
    #pragma unroll
    for (int off = 1; off < 64; off <<= 1) { s += __shfl_xor(s, off); s2 += __shfl_xor(s2, off); }
    __shared__ float sa[4], sb[4];
    int lane = t & 63, wv = t >> 6;
    if (lane == 0) { sa[wv] = s; sb[wv] = s2; }
    __syncthreads();
    s = sa[0]+sa[1]+sa[2]+sa[3];
    s2 = sb[0]+sb[1]+sb[2]+sb[3];
    float mu = s / DMODEL;
    float var = s2 / DMODEL - mu * mu;
    float sc = rsqrtf(var + EPSV);
    unsigned short* ho = hout + (size_t)row * DMODEL + t * 8;
    #pragma unroll
    for (int i = 0; i < 8; ++i) {
        int d = t * 8 + i;
        ho[i] = f2bf((v[i] - mu) * sc * w[d] + b[d]);
    }
}

// ---------------- pipelined bf16 MFMA GEMM: C[M,N] = A[M,K] * B[N,K]^T ----------
// 128x256 tile, BK=64, 8 waves (2x4), ring-3 LDS (144KB), global_load_lds staging
// with pre-swizzled global source (T2), counted vmcnt(6) + 1 barrier per K-tile
// (T4), setprio around MFMA clusters (T5), XCD-chunked block swizzle (T1).
// Within each XCD chunk the traversal is by-FAST (column-major): the ~32
// concurrent blocks on one XCD share a single 1MB B-tile (L2-resident) while
// A panels are served from L3.
// EPI 0: f32. EPI 1: gelu(acc+bias)->bf16. EPI 2: acc+bias+add1+add2->f32. EPI 3: bf16.
#define SLOTSZ 49152
template <int EPI>
__global__ __launch_bounds__(512, 2) void gemm_p(
    const unsigned short* __restrict__ A, const unsigned short* __restrict__ B,
    int M, int N, int K, int nby,
    float* __restrict__ outF, unsigned short* __restrict__ outH,
    const float* __restrict__ bias, const float* __restrict__ add1,
    const float* __restrict__ add2) {
    __shared__ __align__(16) char smem[3 * SLOTSZ];
    int t = threadIdx.x, lane = t & 63, w = t >> 6;
    int nwg = gridDim.x, cpx = nwg >> 3;
    int logical = (blockIdx.x & 7) * cpx + (blockIdx.x >> 3);
    int by = logical % nby, bx = logical / nby;   // by-fast: B-tile reuse in L2
    int brow = by * 128, bcol = bx * 256;
    int wr = w >> 2, wc = w & 3;
    int wrb = wr * 64, wcb = wc * 64;

    // staging source (swizzled): lane l fetches row (l>>3), chunk (l&7)^(l>>3)
    int lr8 = lane >> 3;
    int lch = ((lane & 7) ^ lr8) << 3;          // element offset within 64-elem row
    const unsigned short* pa[2];
    #pragma unroll
    for (int j = 0; j < 2; ++j)
        pa[j] = A + (size_t)(brow + w * 16 + j * 8 + lr8) * K + lch;
    const unsigned short* pb[4];
    #pragma unroll
    for (int j = 0; j < 4; ++j) {
        int r = bcol + w * 32 + j * 8 + lr8;
        if (r > N - 1) r = N - 1;
        pb[j] = B + (size_t)r * K + lch;
    }
    auto stageA = [&](int slot, int j) {
        gll16(pa[j], smem + slot * SLOTSZ + (w * 16 + j * 8) * 128);
        pa[j] += 64;
    };
    auto stageB = [&](int slot, int j) {
        gll16(pb[j], smem + slot * SLOTSZ + 16384 + (w * 32 + j * 8) * 128);
        pb[j] += 64;
    };

    // fragment-read swizzle: byte = row*128 + ((c ^ (row&7))*16), c = ks*4 + (lane>>4)
    int arow = lane & 15;
    int swz0 = (((lane >> 4) ^ (lane & 7)) << 4);

    f32x4 acc[4][4] = {};
    const int NT = K >> 6;
    #pragma unroll
    for (int j = 0; j < 2; ++j) stageA(0, j);
    #pragma unroll
    for (int j = 0; j < 4; ++j) stageB(0, j);
    #pragma unroll
    for (int j = 0; j < 2; ++j) stageA(1, j);
    #pragma unroll
    for (int j = 0; j < 4; ++j) stageB(1, j);

    int slot = 0, slot2 = 2;
    for (int kt = 0; kt < NT; ++kt) {
        if (kt + 1 < NT) { asm volatile("s_waitcnt vmcnt(6)" ::: "memory"); }
        else             { asm volatile("s_waitcnt vmcnt(0)" ::: "memory"); }
        __builtin_amdgcn_s_barrier();
        asm volatile("" ::: "memory");
        const char* Ab = smem + slot * SLOTSZ;
        const char* Bb = Ab + 16384;
        bool st = (kt + 2 < NT);
        // ---- phase 0 (k 0..31) ----
        short8 af[4], bfv[4];
        #pragma unroll
        for (int f = 0; f < 4; ++f)
            af[f] = *(const short8*)(Ab + (wrb + f * 16 + arow) * 128 + swz0);
        #pragma unroll
        for (int n = 0; n < 4; ++n)
            bfv[n] = *(const short8*)(Bb + (wcb + n * 16 + arow) * 128 + swz0);
        if (st) { stageA(slot2, 0); stageA(slot2, 1); stageB(slot2, 0); }
        __builtin_amdgcn_s_setprio(1);
        #pragma unroll
        for (int f = 0; f < 4; ++f)
            #pragma unroll
            for (int n = 0; n < 4; ++n)
                acc[f][n] = __builtin_amdgcn_mfma_f32_16x16x32_bf16(af[f], bfv[n], acc[f][n], 0, 0, 0);
        __builtin_amdgcn_s_setprio(0);
        // ---- phase 1 (k 32..63) ----
        #pragma unroll
        for (int f = 0; f < 4; ++f)
            af[f] = *(const short8*)(Ab + (wrb + f * 16 + arow) * 128 + (swz0 ^ 64));
        #pragma unroll
        for (int n = 0; n < 4; ++n)
            bfv[n] = *(const short8*)(Bb + (wcb + n * 16 + arow) * 128 + (swz0 ^ 64));
        if (st) { stageB(slot2, 1); stageB(slot2, 2); stageB(slot2, 3); }
        __builtin_amdgcn_s_setprio(1);
        #pragma unroll
        for (int f = 0; f < 4; ++f)
            #pragma unroll
            for (int n = 0; n < 4; ++n)
                acc[f][n] = __builtin_amdgcn_mfma_f32_16x16x32_bf16(af[f], bfv[n], acc[f][n], 0, 0, 0);
        __builtin_amdgcn_s_setprio(0);
        slot  = (slot  == 2) ? 0 : slot + 1;
        slot2 = (slot2 == 2) ? 0 : slot2 + 1;
    }

    int rlane = (lane >> 4) << 2, clane = lane & 15;
    #pragma unroll
    for (int f = 0; f < 4; ++f) {
        #pragma unroll
        for (int n = 0; n < 4; ++n) {
            int col = bcol + wcb + n * 16 + clane;
            if (col < N) {
                #pragma unroll
                for (int j = 0; j < 4; ++j) {
                    int row = brow + wrb + f * 16 + rlane + j;
                    size_t idx = (size_t)row * N + col;
                    float v = acc[f][n][j];
                    if constexpr (EPI == 0) {
                        outF[idx] = v;
                    } else if constexpr (EPI == 1) {
                        v += bias[col];
                        float g = 0.5f * v * (1.f + tanhf(0.7978845608f * (v + 0.044715f * v * v * v)));
                        outH[idx] = f2bf(g);
                    } else if constexpr (EPI == 2) {
                        outF[idx] = v + bias[col] + add1[idx] + add2[idx];
                    } else {
                        outH[idx] = f2bf(v);
                    }
                }
            }
        }
    }
}

// ---------------- dt: softplus + dt*A precompute ----------------
__global__ __launch_bounds__(256) void dtk(const unsigned short* __restrict__ zx,
                                           const float* __restrict__ dt_bias,
                                           const float* __restrict__ A_log,
                                           float* __restrict__ dtv, float* __restrict__ dtA) {
    int idx = blockIdx.x * 256 + threadIdx.x;   // < ROWS*NHEADS
    int h = idx & 63;
    size_t row = idx >> 6;
    float raw = bf2f(zx[row * DINPROJ + 10240 + h]) + dt_bias[h];
    float dt = raw > 20.f ? raw : log1pf(expf(raw));
    dtv[idx] = dt;
    dtA[idx] = dt * (-expf(A_log[h]));
}

// 64x64x64 bf16 MFMA: out rows = rows of Al, out cols = rows of Bl, K = inner 64.
static __device__ __forceinline__ void mm64(const unsigned short* Al, const unsigned short* Bl,
                                            f32x4* acc, int w, int lane) {
    int lr = lane & 15, kg = (lane >> 4) << 3;
    #pragma unroll
    for (int ks = 0; ks < 2; ++ks) {
        short8 a = *(const short8*)&Al[(w * 16 + lr) * 64 + ks * 32 + kg];
        #pragma unroll
        for (int fn = 0; fn < 4; ++fn) {
            short8 bb = *(const short8*)&Bl[(fn * 16 + lr) * 64 + ks * 32 + kg];
            acc[fn] = __builtin_amdgcn_mfma_f32_16x16x32_bf16(a, bb, acc[fn], 0, 0, 0);
        }
    }
}

// ---------------- K1: per-(b,h,chunk) intra-chunk work ----------------
__global__ __launch_bounds__(256) void chunk_front(const unsigned short* __restrict__ zx,
                                                   const float* __restrict__ dtv,
                                                   const float* __restrict__ dtA,
                                                   float* __restrict__ pcum,
                                                   unsigned short* __restrict__ ybuf,
                                                   unsigned short* __restrict__ Sbuf) {
    __shared__ __align__(16) unsigned short Cs[64*64], Bsr[64*64], Btr[64*64],
                                            Xtr[64*64], Xw[64*64], Wsm[64*64];
    __shared__ float dts[64], clg[64];
    int t = threadIdx.x, lane = t & 63, w = t >> 6;
    int bid = blockIdx.x;
    int c = bid & 31, h = (bid >> 5) & 63, b = bid >> 11, g = h >> 2;
    int row0 = (b << 11) + (c << 6);

    if (t < 64) {
        dts[t] = dtv[(size_t)(row0 + t) * 64 + h];
        float v = dtA[(size_t)(row0 + t) * 64 + h];
        #pragma unroll
        for (int off = 1; off < 64; off <<= 1) {
            float o = __shfl_up(v, off);
            if (lane >= off) v += o;
        }
        clg[t] = v;
        pcum[(size_t)(row0 + t) * 64 + h] = expf(v);
    }
    ushort4 xr[4];
    #pragma unroll
    for (int i = 0; i < 4; ++i) {
        int q = i * 256 + t, s = q >> 4, d4 = (q & 15) << 2;
        const unsigned short* rp = zx + (size_t)(row0 + s) * DINPROJ;
        ushort4 cv = *(const ushort4*)&rp[6144 + h * 64 + d4];
        *(ushort4*)&Cs[s * 64 + d4] = cv;
        ushort4 bv = *(const ushort4*)&rp[5120 + g * 64 + d4];
        *(ushort4*)&Bsr[s * 64 + d4] = bv;
        Btr[(d4 + 0) * 64 + s] = bv.x; Btr[(d4 + 1) * 64 + s] = bv.y;
        Btr[(d4 + 2) * 64 + s] = bv.z; Btr[(d4 + 3) * 64 + s] = bv.w;
        ushort4 xv = *(const ushort4*)&rp[4096 + g * 64 + d4];
        Xtr[(d4 + 0) * 64 + s] = xv.x; Xtr[(d4 + 1) * 64 + s] = xv.y;
        Xtr[(d4 + 2) * 64 + s] = xv.z; Xtr[(d4 + 3) * 64 + s] = xv.w;
        xr[i] = xv;
    }
    __syncthreads();
    float cl63 = clg[63];
    #pragma unroll
    for (int i = 0; i < 4; ++i) {
        int q = i * 256 + t, s = q >> 4, d4 = (q & 15) << 2;
        float ws = dts[s] * expf(cl63 - clg[s]);
        Xw[(d4 + 0) * 64 + s] = f2bf(bf2f(xr[i].x) * ws);
        Xw[(d4 + 1) * 64 + s] = f2bf(bf2f(xr[i].y) * ws);
        Xw[(d4 + 2) * 64 + s] = f2bf(bf2f(xr[i].z) * ws);
        Xw[(d4 + 3) * 64 + s] = f2bf(bf2f(xr[i].w) * ws);
    }
    __syncthreads();
    f32x4 accG[4] = {};
    mm64(Cs, Bsr, accG, w, lane);
    int rl = (lane >> 4) << 2, cl = lane & 15;
    #pragma unroll
    for (int fn = 0; fn < 4; ++fn) {
        #pragma unroll
        for (int j = 0; j < 4; ++j) {
            int tr = w * 16 + rl + j, rc = fn * 16 + cl;
            float val = 0.f;
            if (rc <= tr) val = accG[fn][j] * expf(clg[tr] - clg[rc]) * dts[rc];
            Wsm[tr * 64 + rc] = f2bf(val);
        }
    }
    __syncthreads();
    f32x4 accY[4] = {};
    mm64(Wsm, Xtr, accY, w, lane);
    f32x4 accS[4] = {};
    mm64(Xw, Btr, accS, w, lane);
    size_t cb = (size_t)((((b << 6) + h) << 5) + c) * 4096;
    #pragma unroll
    for (int fn = 0; fn < 4; ++fn) {
        #pragma unroll
        for (int j = 0; j < 4; ++j) {
            int tr = w * 16 + rl + j, pc = fn * 16 + cl;
            ybuf[(size_t)(row0 + tr) * DINNER + h * 64 + pc] = f2bf(accY[fn][j]);
            Sbuf[cb + tr * 64 + pc] = f2bf(accS[fn][j]);
        }
    }
}

// ---------------- K2: inter-chunk state recurrence (in-place S -> H0) ----------------
__global__ __launch_bounds__(256) void chunk_state(unsigned short* __restrict__ SH,
                                                   const float* __restrict__ pcum) {
    int b = blockIdx.x >> 6, h = blockIdx.x & 63, t = threadIdx.x;
    float H[16];
    #pragma unroll
    for (int j = 0; j < 16; ++j) H[j] = 0.f;
    for (int c = 0; c < NC; ++c) {
        size_t base = (size_t)((((b << 6) + h) << 5) + c) * 4096;
        float Tc = pcum[(size_t)((b << 11) + (c << 6) + 63) * 64 + h];
        #pragma unroll
        for (int j = 0; j < 16; ++j) {
            int e = j * 256 + t;
            unsigned short sv = SH[base + e];
            SH[base + e] = f2bf(H[j]);
            H[j] = H[j] * Tc + bf2f(sv);
        }
    }
}

// ---------------- K3: y += p_t * (C_t . H0) + Dp * x ----------------
__global__ __launch_bounds__(256) void chunk_back(const unsigned short* __restrict__ zx,
                                                  const unsigned short* __restrict__ SH,
                                                  const float* __restrict__ pcum,
                                                  const float* __restrict__ Dp,
                                                  unsigned short* __restrict__ ybuf) {
    __shared__ __align__(16) unsigned short Cs[64*64], Hs[64*64];
    __shared__ float ps[64];
    int t = threadIdx.x, lane = t & 63, w = t >> 6;
    int bid = blockIdx.x;
    int c = bid & 31, h = (bid >> 5) & 63, b = bid >> 11, g = h >> 2;
    int row0 = (b << 11) + (c << 6);
    size_t cb = (size_t)((((b << 6) + h) << 5) + c) * 4096;
    #pragma unroll
    for (int i = 0; i < 4; ++i) {
        int q = i * 256 + t, s = q >> 4, d4 = (q & 15) << 2;
        *(ushort4*)&Cs[s * 64 + d4] =
            *(const ushort4*)&zx[(size_t)(row0 + s) * DINPROJ + 6144 + h * 64 + d4];
        *(ushort4*)&Hs[s * 64 + d4] = *(const ushort4*)&SH[cb + s * 64 + d4];
    }
    if (t < 64) ps[t] = pcum[(size_t)(row0 + t) * 64 + h];
    __syncthreads();
    f32x4 acc[4] = {};
    mm64(Cs, Hs, acc, w, lane);
    float Dph = Dp[h];
    int rl = (lane >> 4) << 2, cl = lane & 15;
    #pragma unroll
    for (int fn = 0; fn < 4; ++fn) {
        #pragma unroll
        for (int j = 0; j < 4; ++j) {
            int tr = w * 16 + rl + j, pc = fn * 16 + cl;
            size_t yi = (size_t)(row0 + tr) * DINNER + h * 64 + pc;
            float xv = bf2f(zx[(size_t)(row0 + tr) * DINPROJ + 4096 + g * 64 + pc]);
            ybuf[yi] = f2bf(bf2f(ybuf[yi]) + acc[fn][j] * ps[tr] + Dph * xv);
        }
    }
}

// ---------------- gate (silu) + RMSNorm -> bf16 yf ----------------
__global__ __launch_bounds__(256) void gate_kernel(const unsigned short* __restrict__ y,
                                                   const unsigned short* __restrict__ zx,
                                                   const float* __restrict__ norm_w,
                                                   unsigned short* __restrict__ yf) {
    int row = blockIdx.x;
    int t = threadIdx.x;
    float v[16];
    float s2 = 0.f;
    #pragma unroll
    for (int i = 0; i < 16; ++i) {
        int d = i * 256 + t;
        float yv = bf2f(y[(size_t)row * DINNER + d]);
        float zv = bf2f(zx[(size_t)row * DINPROJ + d]);
        float gt = zv / (1.f + expf(-zv));
        v[i] = yv * gt;
        s2 += v[i] * v[i];
    }
    #pragma unroll
    for (int off = 1; off < 64; off <<= 1) s2 += __shfl_xor(s2, off);
    __shared__ float sb[4];
    int lane = t & 63, wv = t >> 6;
    if (lane == 0) sb[wv] = s2;
    __syncthreads();
    s2 = sb[0] + sb[1] + sb[2] + sb[3];
    float sc = rsqrtf(s2 / DINNER + EPSV);
    #pragma unroll
    for (int i = 0; i < 16; ++i) {
        int d = i * 256 + t;
        yf[(size_t)row * DINNER + d] = f2bf(v[i] * sc * norm_w[d]);
    }
}

extern "C" void kernel_launch(void* const* d_in, const int* in_sizes, int n_in,
                              void* d_out, int out_size, void* d_ws, size_t ws_size,
                              hipStream_t stream) {
    const float* hid   = (const float*)d_in[0];
    const float* ln_w  = (const float*)d_in[1];
    const float* ln_b  = (const float*)d_in[2];
    const float* w_inp = (const float*)d_in[3];
    const float* dtb   = (const float*)d_in[4];
    const float* A_log = (const float*)d_in[5];
    const float* Dp    = (const float*)d_in[6];
    const float* nw    = (const float*)d_in[7];
    const float* w_out = (const float*)d_in[8];
    const float* w_fc1 = (const float*)d_in[9];
    const float* fc1_b = (const float*)d_in[10];
    const float* w_fc2 = (const float*)d_in[11];
    const float* fc2_b = (const float*)d_in[12];

    char* ws = (char*)d_ws;
    size_t off = 0;
    auto alloc = [&](size_t bytes) { size_t o = off; off += (bytes + 255) & ~(size_t)255; return o; };
    size_t o_h    = alloc((size_t)ROWS * DMODEL * 2);        // h bf16
    size_t o_w    = alloc((size_t)DINPROJ * DMODEL * 2);     // shared weight bf16 buffer
    size_t o_zx   = alloc((size_t)ROWS * DINPROJ * 2);       // zxbcdt bf16 (later: gelu bf16)
    size_t o_dt   = alloc((size_t)ROWS * NHEADS * 4);        // dt f32
    size_t o_dta  = alloc((size_t)ROWS * NHEADS * 4);        // dt*A f32
    size_t o_pc   = alloc((size_t)ROWS * NHEADS * 4);        // pcum f32
    size_t o_y    = alloc((size_t)ROWS * DINNER * 2);        // y bf16 (later: mamba f32 area reuse)
    size_t o_yf   = alloc((size_t)ROWS * DINNER * 2);        // yf bf16
    size_t o_S    = alloc((size_t)BATCH * NHEADS * NC * HEADDIM * DSTATE * 2); // S->H0 bf16

    unsigned short* h_bf  = (unsigned short*)(ws + o_h);
    unsigned short* wbuf  = (unsigned short*)(ws + o_w);
    unsigned short* zx    = (unsigned short*)(ws + o_zx);
    float* dtv            = (float*)(ws + o_dt);
    float* dtA            = (float*)(ws + o_dta);
    float* pcum           = (float*)(ws + o_pc);
    unsigned short* ybuf  = (unsigned short*)(ws + o_y);
    unsigned short* yf    = (unsigned short*)(ws + o_yf);
    unsigned short* Sbuf  = (unsigned short*)(ws + o_S);
    unsigned short* gelu  = (unsigned short*)(ws + o_zx);    // alias: zx dead after gate
    float* mamba          = (float*)(ws + o_y);              // alias: y dead after gate
    float* outF           = (float*)d_out;

    // 1) LayerNorm -> h (bf16)
    ln_kernel<<<ROWS, 256, 0, stream>>>(hid, ln_w, ln_b, h_bf);
    // 2) in_proj GEMM -> zx (bf16); grid = 41 col-tiles x 32 row-tiles
    convk<<<2048, 256, 0, stream>>>(w_inp, wbuf, (DINPROJ * DMODEL) / 4);
    gemm_p<3><<<41 * 32, 512, 0, stream>>>(
        h_bf, wbuf, ROWS, DINPROJ, DMODEL, 32, nullptr, zx, nullptr, nullptr, nullptr);
    // 3) dt softplus + dt*A
    dtk<<<(ROWS * NHEADS) / 256, 256, 0, stream>>>(zx, dtb, A_log, dtv, dtA);
    // 4) chunked SSD scan
    chunk_front<<<BATCH * NHEADS * NC, 256, 0, stream>>>(zx, dtv, dtA, pcum, ybuf, Sbuf);
    chunk_state<<<BATCH * NHEADS, 256, 0, stream>>>(Sbuf, pcum);
    chunk_back<<<BATCH * NHEADS * NC, 256, 0, stream>>>(zx, Sbuf, pcum, Dp, ybuf);
    // 5) gate + RMSNorm -> yf (bf16)
    gate_kernel<<<ROWS, 256, 0, stream>>>(ybuf, zx, nw, yf);
    // 6) out_proj GEMM -> mamba (f32)
    convk<<<2048, 256, 0, stream>>>(w_out, wbuf, (DMODEL * DINNER) / 4);
    gemm_p<0><<<8 * 32, 512, 0, stream>>>(
        yf, wbuf, ROWS, DMODEL, DINNER, 32, mamba, nullptr, nullptr, nullptr, nullptr);
    // 7) fc1 GEMM + gelu -> gelu (bf16, aliases zx)
    convk<<<2048, 256, 0, stream>>>(w_fc1, wbuf, (INTER * DMODEL) / 4);
    gemm_p<1><<<32 * 32, 512, 0, stream>>>(
        h_bf, wbuf, ROWS, INTER, DMODEL, 32, nullptr, gelu, fc1_b, nullptr, nullptr);
    // 8) fc2 GEMM + bias + mamba + residual -> d_out (f32)
    convk<<<2048, 256, 0, stream>>>(w_fc2, wbuf, (DMODEL * INTER) / 4);
    gemm_p<2><<<8 * 32, 512, 0, stream>>>(
        gelu, wbuf, ROWS, DMODEL, INTER, 32, outF, nullptr, fc2_b, mamba, hid);
}